// Round 2
// baseline (6633.250 us; speedup 1.0000x reference)
//
#include <hip/hip_runtime.h>
#include <math.h>

// ---------------------------------------------------------------------------
// SpatioTemporalOutageModel:
//   GCN(14->64) -> GCN(64->64)+county_bias -> LSTM(64->128, T=336) -> MLP(128->64->1)
//
// R1 design (all fp32):
//  - Time-chunked pipeline: for each chunk of Tc timesteps,
//      transform(x@W1) -> agg(relu) -> transform(@W2) -> agg(+county) -> lstm_chunk
//    LSTM h/c state (N x 128 x 2 fp32) carried in workspace between chunks.
//    Tc chosen at launch from ws_size so workspace can NEVER overflow
//    (R1 crash root cause: unchecked 557 MB allocation).
//  - Chunk buffers (~2 x 23-40 MB) stay L2/L3-resident -> GCN stage is
//    cache-bound, not HBM-bound.
//  - Fully deterministic: CSR rows sorted by edge id; degree summed per-node
//    over the sorted row (no float atomics).
//  - LSTM: thread j owns gate row j; W_ih row (64) + W_hh row (128) in VGPRs;
//    x/h/c/g in LDS; 13 nodes per 512-thread block.
// ---------------------------------------------------------------------------

#define T_DIM 336
#define N_DIM 3233
#define E_DIM 20000
#define FEAT  14
#define D_DIM 64
#define H_DIM 128
#define G4    512                 // 4*H
#define ET    (E_DIM + N_DIM)     // edges + self loops = 23233
#define NPB   13                  // nodes per LSTM block

__device__ __forceinline__ float sigf(float x) {
    return 1.f / (1.f + exp2f(-1.4426950408889634f * x));
}
__device__ __forceinline__ float tanhfast(float x) {
    // tanh(x) = 1 - 2/(exp2(2x*log2e)+1). Saturates correctly at +-inf.
    return 1.f - 2.f / (1.f + exp2f(2.8853900817779268f * x));
}

// ---------------- CSR build (deterministic) ----------------

__global__ void k_init(int* cnt, int* fill) {
    int i = blockIdx.x * 256 + threadIdx.x;
    if (i < N_DIM) { cnt[i] = 0; fill[i] = 0; }
}

__global__ void k_cnt(const int* __restrict__ ei, int* cnt) {
    int e = blockIdx.x * 256 + threadIdx.x;
    if (e < E_DIM) atomicAdd(&cnt[ei[E_DIM + e]], 1);   // dst = ei[1][e]
}

// exclusive scan of row lengths (cnt[n]+1 self loop) -> rowp[N_DIM+1]
__global__ void k_scan(const int* __restrict__ cnt, int* __restrict__ rowp) {
    __shared__ int csum[1024];
    int tid = threadIdx.x;
    int base = tid * 4;
    int v[4];
    int s = 0;
    #pragma unroll
    for (int m = 0; m < 4; m++) {
        int idx = base + m;
        int len = (idx < N_DIM) ? (cnt[idx] + 1) : 0;
        v[m] = s; s += len;
    }
    csum[tid] = s;
    __syncthreads();
    for (int off = 1; off < 1024; off <<= 1) {
        int t2 = (tid >= off) ? csum[tid - off] : 0;
        __syncthreads();
        csum[tid] += t2;
        __syncthreads();
    }
    int pre = (tid > 0) ? csum[tid - 1] : 0;
    #pragma unroll
    for (int m = 0; m < 4; m++) {
        int idx = base + m;
        if (idx <= N_DIM) rowp[idx] = pre + v[m];
    }
}

__global__ void k_fill(const int* __restrict__ ei, const int* __restrict__ rowp,
                       int* fill, int* __restrict__ eid) {
    int e = blockIdx.x * 256 + threadIdx.x;
    if (e < ET) {
        int d = (e < E_DIM) ? ei[E_DIM + e] : (e - E_DIM);
        int p = rowp[d] + atomicAdd(&fill[d], 1);
        eid[p] = e;   // row membership is atomic-ordered, but k_sortdeg re-sorts
    }
}

// sort each row by edge id (determinism), then deg = sum(w) over sorted row
__global__ void k_sortdeg(const float* __restrict__ ew, const int* __restrict__ rowp,
                          int* __restrict__ eid, float* __restrict__ dis) {
    int n = blockIdx.x * 256 + threadIdx.x;
    if (n >= N_DIM) return;
    int p0 = rowp[n], p1 = rowp[n + 1];
    for (int i = p0 + 1; i < p1; i++) {
        int key = eid[i];
        int j = i - 1;
        while (j >= p0 && eid[j] > key) { eid[j + 1] = eid[j]; j--; }
        eid[j + 1] = key;
    }
    float deg = 0.f;
    for (int p = p0; p < p1; p++) {
        int e = eid[p];
        deg += (e < E_DIM) ? ew[e] : 1.0f;
    }
    dis[n] = rsqrtf(deg);   // deg >= 1 (self loop weight 1)
}

__global__ void k_csrmat(const int* __restrict__ ei, const float* __restrict__ ew,
                         const float* __restrict__ dis, const int* __restrict__ rowp,
                         const int* __restrict__ eid, int* __restrict__ csrc,
                         float* __restrict__ cnrm) {
    int n = blockIdx.x * 256 + threadIdx.x;
    if (n >= N_DIM) return;
    float dn = dis[n];
    int p0 = rowp[n], p1 = rowp[n + 1];
    for (int p = p0; p < p1; p++) {
        int e = eid[p];
        int s; float w;
        if (e < E_DIM) { s = ei[e]; w = ew[e]; }
        else           { s = e - E_DIM; w = 1.0f; }
        csrc[p] = s;
        cnrm[p] = dis[s] * w * dn;
    }
}

// ---------------- GCN dense transform: out[r][j] = sum_k in[r][k]*W[k][j] ----------------
// lane j holds W column j in registers; 2 rows per wave for ILP.
template <int K>
__global__ void k_transform(const float* __restrict__ in, const float* __restrict__ W,
                            float* __restrict__ out, long rows) {
    int lane = threadIdx.x & 63;
    long wid = ((long)blockIdx.x * 256 + threadIdx.x) >> 6;
    float wc[K];
    #pragma unroll
    for (int k = 0; k < K; k++) wc[k] = W[k * 64 + lane];
    long r0 = wid * 2;
    if (r0 >= rows) return;
    long r1 = r0 + 1;
    bool has1 = (r1 < rows);
    const float* p0 = in + r0 * K;
    const float* p1 = in + (has1 ? r1 : r0) * K;
    float a0 = 0.f, a1 = 0.f;
    #pragma unroll
    for (int k = 0; k < K; k++) { a0 += p0[k] * wc[k]; a1 += p1[k] * wc[k]; }
    out[r0 * 64 + lane] = a0;
    if (has1) out[r1 * 64 + lane] = a1;
}

// ---------------- GCN aggregation over a chunk of Tc timesteps ----------------
// out[t,n,:] = bias (+county) + sum_p nrm[p]*hw[t,csrc[p],:]
__global__ void k_agg(const float* __restrict__ hw, const int* __restrict__ rowp,
                      const int* __restrict__ csrc, const float* __restrict__ cnrm,
                      const float* __restrict__ bias, const float* __restrict__ county,
                      float* __restrict__ out, int do_relu, long rows) {
    int lane = threadIdx.x & 63;
    long wid = ((long)blockIdx.x * 256 + threadIdx.x) >> 6;
    if (wid >= rows) return;
    int t = (int)(wid / N_DIM);                 // chunk-local t
    int n = (int)(wid - (long)t * N_DIM);
    float acc = bias[lane];
    if (county) acc += county[(long)n * 64 + lane];
    int p0 = rowp[n], p1 = rowp[n + 1];
    const float* base = hw + (long)t * N_DIM * 64;
    for (int p = p0; p < p1; p++) {
        int s = csrc[p];
        float w = cnrm[p];
        acc += w * base[(long)s * 64 + lane];
    }
    if (do_relu) acc = fmaxf(acc, 0.f);
    out[wid * 64 + lane] = acc;
}

// ---------------- LSTM chunk + (optional) MLP head ----------------

template <int G>
__device__ __forceinline__ void gates_group(
    int ng, int tid, float bias,
    const float (&wih)[64], const float (&whh)[128],
    const float (*xs)[64], const float (*hs)[128], float (*gs)[G4]) {
    float acc[G];
    #pragma unroll
    for (int g = 0; g < G; g++) acc[g] = bias;
    #pragma unroll
    for (int k4 = 0; k4 < 16; k4++) {
        #pragma unroll
        for (int g = 0; g < G; g++) {
            float4 v = reinterpret_cast<const float4*>(xs[ng + g])[k4];
            acc[g] += v.x * wih[4 * k4 + 0];
            acc[g] += v.y * wih[4 * k4 + 1];
            acc[g] += v.z * wih[4 * k4 + 2];
            acc[g] += v.w * wih[4 * k4 + 3];
        }
    }
    #pragma unroll
    for (int k4 = 0; k4 < 32; k4++) {
        #pragma unroll
        for (int g = 0; g < G; g++) {
            float4 v = reinterpret_cast<const float4*>(hs[ng + g])[k4];
            acc[g] += v.x * whh[4 * k4 + 0];
            acc[g] += v.y * whh[4 * k4 + 1];
            acc[g] += v.z * whh[4 * k4 + 2];
            acc[g] += v.w * whh[4 * k4 + 3];
        }
    }
    #pragma unroll
    for (int g = 0; g < G; g++) gs[ng + g][tid] = acc[g];
}

__global__ __launch_bounds__(512, 2) void k_lstm(
    const float* __restrict__ emb, const float* __restrict__ Wih,
    const float* __restrict__ Whh, const float* __restrict__ bih,
    const float* __restrict__ bhh, const float* __restrict__ Wm1,
    const float* __restrict__ bm1, const float* __restrict__ Wm2,
    const float* __restrict__ bm2, float* __restrict__ Hst,
    float* __restrict__ Cst, int tc, int do_init, int do_head,
    float* __restrict__ out) {
    __shared__ __align__(16) float xs[NPB][64];
    __shared__ __align__(16) float hs[NPB][H_DIM];
    __shared__ __align__(16) float cs[NPB][H_DIM];
    __shared__ __align__(16) float gs[NPB][G4];
    __shared__ __align__(16) float zs[NPB][64];
    int tid = threadIdx.x;
    int nb = blockIdx.x * NPB;
    int cnt = min(NPB, N_DIM - nb);

    // thread tid owns gate row tid: weights into VGPRs
    float wih[64], whh[128];
    #pragma unroll
    for (int k = 0; k < 64; k++) wih[k] = Wih[tid * 64 + k];
    #pragma unroll
    for (int k = 0; k < 128; k++) whh[k] = Whh[tid * 128 + k];
    float bias = bih[tid] + bhh[tid];

    // load or init state
    for (int i = tid; i < NPB * H_DIM; i += 512) {
        int n = i >> 7, u = i & 127;
        bool live = (!do_init) && (n < cnt);
        (&hs[0][0])[i] = live ? Hst[(long)(nb + n) * H_DIM + u] : 0.f;
        (&cs[0][0])[i] = live ? Cst[(long)(nb + n) * H_DIM + u] : 0.f;
    }

    for (int t = 0; t < tc; t++) {
        // stage x_t for this block's nodes
        for (int i = tid; i < NPB * 64; i += 512) {
            int n = i >> 6, k = i & 63;
            (&xs[0][0])[i] = (n < cnt) ? emb[(((long)t * N_DIM) + nb + n) * 64 + k] : 0.f;
        }
        __syncthreads();   // x staged; h/c from previous step visible

        gates_group<4>(0, tid, bias, wih, whh, xs, hs, gs);
        gates_group<4>(4, tid, bias, wih, whh, xs, hs, gs);
        gates_group<4>(8, tid, bias, wih, whh, xs, hs, gs);
        gates_group<1>(12, tid, bias, wih, whh, xs, hs, gs);
        __syncthreads();   // g ready

        for (int i = tid; i < cnt * H_DIM; i += 512) {
            int n = i >> 7, u = i & 127;
            float gi = gs[n][u];
            float gf = gs[n][H_DIM + u];
            float gg = gs[n][2 * H_DIM + u];
            float go = gs[n][3 * H_DIM + u];
            float c = sigf(gf) * cs[n][u] + sigf(gi) * tanhfast(gg);
            float h = sigf(go) * tanhfast(c);
            cs[n][u] = c;
            hs[n][u] = h;
        }
        // next iteration's top barrier orders these writes before gate reads
    }
    __syncthreads();

    // persist state
    for (int i = tid; i < cnt * H_DIM; i += 512) {
        int n = i >> 7, u = i & 127;
        Hst[(long)(nb + n) * H_DIM + u] = hs[n][u];
        Cst[(long)(nb + n) * H_DIM + u] = cs[n][u];
    }

    if (!do_head) return;

    // MLP: z = relu(h @ Wm1 + bm1); out = z @ Wm2 + bm2
    for (int i = tid; i < cnt * 64; i += 512) {
        int n = i >> 6, m = i & 63;
        float a = bm1[m];
        #pragma unroll 8
        for (int k = 0; k < H_DIM; k++) a += hs[n][k] * Wm1[k * 64 + m];
        zs[n][m] = fmaxf(a, 0.f);
    }
    __syncthreads();
    if (tid < cnt) {
        float a = bm2[0];
        #pragma unroll 8
        for (int m = 0; m < 64; m++) a += zs[tid][m] * Wm2[m];
        out[nb + tid] = a;
    }
}

// ---------------------------------------------------------------------------

extern "C" void kernel_launch(void* const* d_in, const int* in_sizes, int n_in,
                              void* d_out, int out_size, void* d_ws, size_t ws_size,
                              hipStream_t stream) {
    const float* x   = (const float*)d_in[0];
    const int*   ei  = (const int*)d_in[1];
    const float* ew  = (const float*)d_in[2];
    const float* W1  = (const float*)d_in[3];
    const float* b1  = (const float*)d_in[4];
    const float* W2  = (const float*)d_in[5];
    const float* b2  = (const float*)d_in[6];
    const float* cb  = (const float*)d_in[7];
    const float* Wih = (const float*)d_in[8];
    const float* Whh = (const float*)d_in[9];
    const float* bih = (const float*)d_in[10];
    const float* bhh = (const float*)d_in[11];
    const float* Wm1 = (const float*)d_in[12];
    const float* bm1 = (const float*)d_in[13];
    const float* Wm2 = (const float*)d_in[14];
    const float* bm2 = (const float*)d_in[15];
    float* out = (float*)d_out;
    (void)in_sizes; (void)n_in; (void)out_size;

    char* ws = (char*)d_ws;
    size_t off = 0;
    auto alloc = [&](size_t bytes) -> char* {
        char* p = ws + off;
        off = (off + bytes + 255) & ~(size_t)255;
        return p;
    };
    float* dis  = (float*)alloc(N_DIM * 4);
    int*   cnt  = (int*)alloc(N_DIM * 4);
    int*   fill = (int*)alloc(N_DIM * 4);
    int*   rowp = (int*)alloc((N_DIM + 1) * 4);
    int*   eid  = (int*)alloc(ET * 4);
    int*   csrc = (int*)alloc(ET * 4);
    float* cnrm = (float*)alloc(ET * 4);
    float* Hst  = (float*)alloc((size_t)N_DIM * H_DIM * 4);
    float* Cst  = (float*)alloc((size_t)N_DIM * H_DIM * 4);

    // pick largest time-chunk Tc (dividing 336) whose two buffers fit ws_size
    const int cand[] = {48, 28, 16, 8, 4, 2, 1};
    int Tc = 1;
    for (int i = 0; i < 7; i++) {
        size_t chunkBytes = (size_t)cand[i] * N_DIM * 64 * 4;
        size_t need = off + 2 * (chunkBytes + 256) + 1024;
        if (need <= ws_size) { Tc = cand[i]; break; }
    }
    size_t chunkBytes = (size_t)Tc * N_DIM * 64 * 4;
    float* bufA = (float*)alloc(chunkBytes);
    float* bufB = (float*)alloc(chunkBytes);

    // --- CSR build (deterministic) ---
    k_init<<<(N_DIM + 255) / 256, 256, 0, stream>>>(cnt, fill);
    k_cnt<<<(E_DIM + 255) / 256, 256, 0, stream>>>(ei, cnt);
    k_scan<<<1, 1024, 0, stream>>>(cnt, rowp);
    k_fill<<<(ET + 255) / 256, 256, 0, stream>>>(ei, rowp, fill, eid);
    k_sortdeg<<<(N_DIM + 255) / 256, 256, 0, stream>>>(ew, rowp, eid, dis);
    k_csrmat<<<(N_DIM + 255) / 256, 256, 0, stream>>>(ei, ew, dis, rowp, eid, csrc, cnrm);

    long rows = (long)Tc * N_DIM;
    int tblocks = (int)(((rows + 1) / 2 + 3) / 4);   // 2 rows/wave, 4 waves/block
    int ablocks = (int)((rows + 3) / 4);             // 1 row/wave, 4 waves/block
    int lblocks = (N_DIM + NPB - 1) / NPB;
    int nChunks = T_DIM / Tc;

    for (int c = 0; c < nChunks; c++) {
        long t0 = (long)c * Tc;
        // GCN1: bufA = x@W1 ; bufB = relu(agg(bufA) + b1)
        k_transform<FEAT><<<tblocks, 256, 0, stream>>>(x + t0 * N_DIM * FEAT, W1, bufA, rows);
        k_agg<<<ablocks, 256, 0, stream>>>(bufA, rowp, csrc, cnrm, b1, nullptr, bufB, 1, rows);
        // GCN2: bufA = bufB@W2 ; bufB = agg(bufA) + b2 + county_bias
        k_transform<D_DIM><<<tblocks, 256, 0, stream>>>(bufB, W2, bufA, rows);
        k_agg<<<ablocks, 256, 0, stream>>>(bufA, rowp, csrc, cnrm, b2, cb, bufB, 0, rows);
        // LSTM chunk (+ head on last chunk)
        k_lstm<<<lblocks, 512, 0, stream>>>(bufB, Wih, Whh, bih, bhh, Wm1, bm1, Wm2, bm2,
                                            Hst, Cst, Tc, c == 0 ? 1 : 0,
                                            c == nChunks - 1 ? 1 : 0, out);
    }
}

// Round 3
// 3339.962 us; speedup vs baseline: 1.9860x; 1.9860x over previous
//
#include <hip/hip_runtime.h>
#include <math.h>

// ---------------------------------------------------------------------------
// SpatioTemporalOutageModel:
//   GCN(14->64) -> GCN(64->64)+county_bias -> LSTM(64->128, T=336) -> MLP(128->64->1)
//
// R3: LSTM moved to f16 MFMA (fp32 accumulate).
//  - Per block: 16 nodes, 512 thr (8 waves). Wave w owns gates [64w,64w+64).
//  - Weight B-fragments (f16x8 x 24) preloaded into VGPRs once (R2 showed the
//    fp32 path's weights never stayed in registers: VGPR_Count=124 < 192).
//  - A operand = concat(x,h) in LDS f16 [16][200] (200 = 192+8 pad -> uniform
//    8-phase ds_read_b128, no bank conflicts).
//  - Gate pre-activations gs[16][512] f32 in LDS; c-state in 4 VGPRs/thread.
//  - MFMA layouts (gfx950 16x16x32): C/D col=lane&15 row=4*(lane>>4)+reg
//    [m89-verified]; A[m][k]: lane=16*(k/8)+m; B[k][n]: lane=16*(k/8)+n.
//  - GCN2 agg writes f16 emb directly (LSTM A operand dtype).
// ---------------------------------------------------------------------------

#define T_DIM 336
#define N_DIM 3233
#define E_DIM 20000
#define FEAT  14
#define D_DIM 64
#define H_DIM 128
#define ET    (E_DIM + N_DIM)     // edges + self loops = 23233

typedef _Float16 f16;
typedef _Float16 half8_t __attribute__((ext_vector_type(8)));
typedef _Float16 half4_t __attribute__((ext_vector_type(4)));
typedef float float4_t __attribute__((ext_vector_type(4)));

__device__ __forceinline__ float sigf(float x) {
    return 1.f / (1.f + exp2f(-1.4426950408889634f * x));
}
__device__ __forceinline__ float tanhfast(float x) {
    return 1.f - 2.f / (1.f + exp2f(2.8853900817779268f * x));
}

// ---------------- CSR build (deterministic) ----------------

__global__ void k_init(int* cnt, int* fill) {
    int i = blockIdx.x * 256 + threadIdx.x;
    if (i < N_DIM) { cnt[i] = 0; fill[i] = 0; }
}

__global__ void k_cnt(const int* __restrict__ ei, int* cnt) {
    int e = blockIdx.x * 256 + threadIdx.x;
    if (e < E_DIM) atomicAdd(&cnt[ei[E_DIM + e]], 1);
}

__global__ void k_scan(const int* __restrict__ cnt, int* __restrict__ rowp) {
    __shared__ int csum[1024];
    int tid = threadIdx.x;
    int base = tid * 4;
    int v[4];
    int s = 0;
    #pragma unroll
    for (int m = 0; m < 4; m++) {
        int idx = base + m;
        int len = (idx < N_DIM) ? (cnt[idx] + 1) : 0;
        v[m] = s; s += len;
    }
    csum[tid] = s;
    __syncthreads();
    for (int off = 1; off < 1024; off <<= 1) {
        int t2 = (tid >= off) ? csum[tid - off] : 0;
        __syncthreads();
        csum[tid] += t2;
        __syncthreads();
    }
    int pre = (tid > 0) ? csum[tid - 1] : 0;
    #pragma unroll
    for (int m = 0; m < 4; m++) {
        int idx = base + m;
        if (idx <= N_DIM) rowp[idx] = pre + v[m];
    }
}

__global__ void k_fill(const int* __restrict__ ei, const int* __restrict__ rowp,
                       int* fill, int* __restrict__ eid) {
    int e = blockIdx.x * 256 + threadIdx.x;
    if (e < ET) {
        int d = (e < E_DIM) ? ei[E_DIM + e] : (e - E_DIM);
        int p = rowp[d] + atomicAdd(&fill[d], 1);
        eid[p] = e;
    }
}

__global__ void k_sortdeg(const float* __restrict__ ew, const int* __restrict__ rowp,
                          int* __restrict__ eid, float* __restrict__ dis) {
    int n = blockIdx.x * 256 + threadIdx.x;
    if (n >= N_DIM) return;
    int p0 = rowp[n], p1 = rowp[n + 1];
    for (int i = p0 + 1; i < p1; i++) {
        int key = eid[i];
        int j = i - 1;
        while (j >= p0 && eid[j] > key) { eid[j + 1] = eid[j]; j--; }
        eid[j + 1] = key;
    }
    float deg = 0.f;
    for (int p = p0; p < p1; p++) {
        int e = eid[p];
        deg += (e < E_DIM) ? ew[e] : 1.0f;
    }
    dis[n] = rsqrtf(deg);
}

__global__ void k_csrmat(const int* __restrict__ ei, const float* __restrict__ ew,
                         const float* __restrict__ dis, const int* __restrict__ rowp,
                         const int* __restrict__ eid, int* __restrict__ csrc,
                         float* __restrict__ cnrm) {
    int n = blockIdx.x * 256 + threadIdx.x;
    if (n >= N_DIM) return;
    float dn = dis[n];
    int p0 = rowp[n], p1 = rowp[n + 1];
    for (int p = p0; p < p1; p++) {
        int e = eid[p];
        int s; float w;
        if (e < E_DIM) { s = ei[e]; w = ew[e]; }
        else           { s = e - E_DIM; w = 1.0f; }
        csrc[p] = s;
        cnrm[p] = dis[s] * w * dn;
    }
}

// ---------------- GCN dense transform ----------------
template <int K>
__global__ void k_transform(const float* __restrict__ in, const float* __restrict__ W,
                            float* __restrict__ out, long rows) {
    int lane = threadIdx.x & 63;
    long wid = ((long)blockIdx.x * 256 + threadIdx.x) >> 6;
    float wc[K];
    #pragma unroll
    for (int k = 0; k < K; k++) wc[k] = W[k * 64 + lane];
    long r0 = wid * 2;
    if (r0 >= rows) return;
    long r1 = r0 + 1;
    bool has1 = (r1 < rows);
    const float* p0 = in + r0 * K;
    const float* p1 = in + (has1 ? r1 : r0) * K;
    float a0 = 0.f, a1 = 0.f;
    #pragma unroll
    for (int k = 0; k < K; k++) { a0 += p0[k] * wc[k]; a1 += p1[k] * wc[k]; }
    out[r0 * 64 + lane] = a0;
    if (has1) out[r1 * 64 + lane] = a1;
}

// ---------------- GCN aggregation ----------------
template <typename OutT>
__global__ void k_agg(const float* __restrict__ hw, const int* __restrict__ rowp,
                      const int* __restrict__ csrc, const float* __restrict__ cnrm,
                      const float* __restrict__ bias, const float* __restrict__ county,
                      OutT* __restrict__ out, int do_relu, long rows) {
    int lane = threadIdx.x & 63;
    long wid = ((long)blockIdx.x * 256 + threadIdx.x) >> 6;
    if (wid >= rows) return;
    int t = (int)(wid / N_DIM);
    int n = (int)(wid - (long)t * N_DIM);
    float acc = bias[lane];
    if (county) acc += county[(long)n * 64 + lane];
    int p0 = rowp[n], p1 = rowp[n + 1];
    const float* base = hw + (long)t * N_DIM * 64;
    for (int p = p0; p < p1; p++) {
        int s = csrc[p];
        float w = cnrm[p];
        acc += w * base[(long)s * 64 + lane];
    }
    if (do_relu) acc = fmaxf(acc, 0.f);
    out[wid * 64 + lane] = (OutT)acc;
}

// ---------------- LSTM chunk (f16 MFMA) + optional MLP head ----------------

__global__ __launch_bounds__(512, 2) void k_lstm(
    const f16* __restrict__ emb,                 // [tc][N][64] f16
    const float* __restrict__ Wih, const float* __restrict__ Whh,
    const float* __restrict__ bih, const float* __restrict__ bhh,
    const float* __restrict__ Wm1, const float* __restrict__ bm1,
    const float* __restrict__ Wm2, const float* __restrict__ bm2,
    float* __restrict__ Hst, float* __restrict__ Cst,
    int tc, int do_init, int do_head, float* __restrict__ out) {
    __shared__ __align__(16) f16   xh[16][200];   // [node][k]: k<64 x, 64..191 h, pad 8
    __shared__ __align__(16) float gs[16][512];   // gate pre-activations / reused f32 h + z

    int tid = threadIdx.x;
    int wv = tid >> 6, lane = tid & 63, q = lane >> 4, r = lane & 15;
    int nb = blockIdx.x * 16;
    int cnt = min(16, N_DIM - nb);

    // ---- preload weight B-fragments into VGPRs: wf[ct][ks] ----
    // gate g = 64*wv + 16*ct + r ; k = 32*ks + 8*q + j   (k<64: Wih, else Whh)
    half8_t wf[4][6];
    float bias[4];
    #pragma unroll
    for (int ct = 0; ct < 4; ct++) {
        int g = 64 * wv + 16 * ct + r;
        bias[ct] = bih[g] + bhh[g];
        #pragma unroll
        for (int ks = 0; ks < 6; ks++) {
            const float* src = (ks < 2) ? (Wih + (long)g * 64 + 32 * ks + 8 * q)
                                        : (Whh + (long)g * 128 + 32 * (ks - 2) + 8 * q);
            #pragma unroll
            for (int j = 0; j < 8; j++) wf[ct][ks][j] = (f16)src[j];
        }
    }

    // ---- state: thread owns (en, eu..eu+3); c,h in VGPRs ----
    int en = tid >> 5, eu = (tid & 31) << 2;
    float c0, c1, c2, c3, h0, h1, h2, h3;
    if (!do_init && en < cnt) {
        const float4* hp = (const float4*)(Hst + (long)(nb + en) * H_DIM + eu);
        const float4* cp = (const float4*)(Cst + (long)(nb + en) * H_DIM + eu);
        float4 hq = *hp, cq = *cp;
        h0 = hq.x; h1 = hq.y; h2 = hq.z; h3 = hq.w;
        c0 = cq.x; c1 = cq.y; c2 = cq.z; c3 = cq.w;
    } else {
        h0 = h1 = h2 = h3 = c0 = c1 = c2 = c3 = 0.f;
    }
    {
        half4_t hv; hv[0] = (f16)h0; hv[1] = (f16)h1; hv[2] = (f16)h2; hv[3] = (f16)h3;
        *(half4_t*)&xh[en][64 + eu] = hv;
    }

    for (int t = 0; t < tc; t++) {
        // ---- stage x_t (f16, zero-pad dead nodes) ----
        if (tid < 256) {
            int n = tid >> 4, cc = (tid & 15) << 2;
            half4_t xv = {0, 0, 0, 0};
            if (n < cnt)
                xv = *(const half4_t*)(emb + ((long)t * N_DIM + nb + n) * 64 + cc);
            *(half4_t*)&xh[n][cc] = xv;
        }
        __syncthreads();   // x + h writes visible to all MFMA reads

        // ---- A-fragments: lane holds xh[r][32*ks+8*q .. +7] ----
        half8_t a[6];
        #pragma unroll
        for (int ks = 0; ks < 6; ks++)
            a[ks] = *(const half8_t*)&xh[r][32 * ks + 8 * q];

        float4_t acc[4];
        #pragma unroll
        for (int ct = 0; ct < 4; ct++) {
            acc[ct][0] = bias[ct]; acc[ct][1] = bias[ct];
            acc[ct][2] = bias[ct]; acc[ct][3] = bias[ct];
        }
        #pragma unroll
        for (int ks = 0; ks < 6; ks++) {
            #pragma unroll
            for (int ct = 0; ct < 4; ct++)
                acc[ct] = __builtin_amdgcn_mfma_f32_16x16x32_f16(a[ks], wf[ct][ks], acc[ct], 0, 0, 0);
        }
        // ---- write gates: C row = 4*q+reg (node), col = gate ----
        #pragma unroll
        for (int ct = 0; ct < 4; ct++) {
            int gcol = 64 * wv + 16 * ct + r;
            #pragma unroll
            for (int reg = 0; reg < 4; reg++)
                gs[4 * q + reg][gcol] = acc[ct][reg];
        }
        __syncthreads();   // gates visible

        // ---- elementwise state update (all f32) ----
        float4 gi = *(float4*)&gs[en][eu];
        float4 gf = *(float4*)&gs[en][H_DIM + eu];
        float4 gg = *(float4*)&gs[en][2 * H_DIM + eu];
        float4 go = *(float4*)&gs[en][3 * H_DIM + eu];
        c0 = sigf(gf.x) * c0 + sigf(gi.x) * tanhfast(gg.x); h0 = sigf(go.x) * tanhfast(c0);
        c1 = sigf(gf.y) * c1 + sigf(gi.y) * tanhfast(gg.y); h1 = sigf(go.y) * tanhfast(c1);
        c2 = sigf(gf.z) * c2 + sigf(gi.z) * tanhfast(gg.z); h2 = sigf(go.z) * tanhfast(c2);
        c3 = sigf(gf.w) * c3 + sigf(gi.w) * tanhfast(gg.w); h3 = sigf(go.w) * tanhfast(c3);
        half4_t hv; hv[0] = (f16)h0; hv[1] = (f16)h1; hv[2] = (f16)h2; hv[3] = (f16)h3;
        *(half4_t*)&xh[en][64 + eu] = hv;
        // next loop's barrier (after stage-x) orders these before MFMA reads
    }
    __syncthreads();   // all elementwise done before gs reuse

    // persist f32 state
    if (en < cnt) {
        float4 hq = {h0, h1, h2, h3}, cq = {c0, c1, c2, c3};
        *(float4*)&Hst[(long)(nb + en) * H_DIM + eu] = hq;
        *(float4*)&Cst[(long)(nb + en) * H_DIM + eu] = cq;
    }
    if (!do_head) return;

    // stash f32 h into gs[node][0..127]
    *(float4*)&gs[en][eu] = (float4){h0, h1, h2, h3};
    __syncthreads();

    // z = relu(h @ Wm1 + bm1) -> gs[node][128..191]
    for (int i = tid; i < 16 * 64; i += 512) {
        int n = i >> 6, m = i & 63;
        float aZ = bm1[m];
        #pragma unroll 8
        for (int k = 0; k < H_DIM; k++) aZ += gs[n][k] * Wm1[k * 64 + m];
        gs[n][128 + m] = fmaxf(aZ, 0.f);
    }
    __syncthreads();
    if (tid < cnt) {
        float aO = bm2[0];
        #pragma unroll 8
        for (int m = 0; m < 64; m++) aO += gs[tid][128 + m] * Wm2[m];
        out[nb + tid] = aO;
    }
}

// ---------------------------------------------------------------------------

extern "C" void kernel_launch(void* const* d_in, const int* in_sizes, int n_in,
                              void* d_out, int out_size, void* d_ws, size_t ws_size,
                              hipStream_t stream) {
    const float* x   = (const float*)d_in[0];
    const int*   ei  = (const int*)d_in[1];
    const float* ew  = (const float*)d_in[2];
    const float* W1  = (const float*)d_in[3];
    const float* b1  = (const float*)d_in[4];
    const float* W2  = (const float*)d_in[5];
    const float* b2  = (const float*)d_in[6];
    const float* cb  = (const float*)d_in[7];
    const float* Wih = (const float*)d_in[8];
    const float* Whh = (const float*)d_in[9];
    const float* bih = (const float*)d_in[10];
    const float* bhh = (const float*)d_in[11];
    const float* Wm1 = (const float*)d_in[12];
    const float* bm1 = (const float*)d_in[13];
    const float* Wm2 = (const float*)d_in[14];
    const float* bm2 = (const float*)d_in[15];
    float* out = (float*)d_out;
    (void)in_sizes; (void)n_in; (void)out_size;

    char* ws = (char*)d_ws;
    size_t off = 0;
    auto alloc = [&](size_t bytes) -> char* {
        char* p = ws + off;
        off = (off + bytes + 255) & ~(size_t)255;
        return p;
    };
    float* dis  = (float*)alloc(N_DIM * 4);
    int*   cnt  = (int*)alloc(N_DIM * 4);
    int*   fill = (int*)alloc(N_DIM * 4);
    int*   rowp = (int*)alloc((N_DIM + 1) * 4);
    int*   eid  = (int*)alloc(ET * 4);
    int*   csrc = (int*)alloc(ET * 4);
    float* cnrm = (float*)alloc(ET * 4);
    float* Hst  = (float*)alloc((size_t)N_DIM * H_DIM * 4);
    float* Cst  = (float*)alloc((size_t)N_DIM * H_DIM * 4);

    // largest Tc (dividing 336) whose two fp32 chunk buffers fit ws_size
    const int cand[] = {48, 28, 16, 8, 4, 2, 1};
    int Tc = 1;
    for (int i = 0; i < 7; i++) {
        size_t chunkBytes = (size_t)cand[i] * N_DIM * 64 * 4;
        size_t need = off + 2 * (chunkBytes + 256) + 1024;
        if (need <= ws_size) { Tc = cand[i]; break; }
    }
    size_t chunkBytes = (size_t)Tc * N_DIM * 64 * 4;
    float* bufA = (float*)alloc(chunkBytes);
    float* bufB = (float*)alloc(chunkBytes);
    f16*   bufC = (f16*)bufB;      // agg2 writes f16 into bufB's space

    k_init<<<(N_DIM + 255) / 256, 256, 0, stream>>>(cnt, fill);
    k_cnt<<<(E_DIM + 255) / 256, 256, 0, stream>>>(ei, cnt);
    k_scan<<<1, 1024, 0, stream>>>(cnt, rowp);
    k_fill<<<(ET + 255) / 256, 256, 0, stream>>>(ei, rowp, fill, eid);
    k_sortdeg<<<(N_DIM + 255) / 256, 256, 0, stream>>>(ew, rowp, eid, dis);
    k_csrmat<<<(N_DIM + 255) / 256, 256, 0, stream>>>(ei, ew, dis, rowp, eid, csrc, cnrm);

    long rows = (long)Tc * N_DIM;
    int tblocks = (int)(((rows + 1) / 2 + 3) / 4);
    int ablocks = (int)((rows + 3) / 4);
    int lblocks = (N_DIM + 15) / 16;
    int nChunks = T_DIM / Tc;

    for (int c = 0; c < nChunks; c++) {
        long t0 = (long)c * Tc;
        k_transform<FEAT><<<tblocks, 256, 0, stream>>>(x + t0 * N_DIM * FEAT, W1, bufA, rows);
        k_agg<float><<<ablocks, 256, 0, stream>>>(bufA, rowp, csrc, cnrm, b1, nullptr, bufB, 1, rows);
        k_transform<D_DIM><<<tblocks, 256, 0, stream>>>(bufB, W2, bufA, rows);
        k_agg<f16><<<ablocks, 256, 0, stream>>>(bufA, rowp, csrc, cnrm, b2, cb, bufC, 0, rows);
        k_lstm<<<lblocks, 512, 0, stream>>>(bufC, Wih, Whh, bih, bhh, Wm1, bm1, Wm2, bm2,
                                            Hst, Cst, Tc, c == 0 ? 1 : 0,
                                            c == nChunks - 1 ? 1 : 0, out);
    }
}

// Round 4
// 2214.432 us; speedup vs baseline: 2.9955x; 1.5083x over previous
//
#include <hip/hip_runtime.h>
#include <math.h>

// ---------------------------------------------------------------------------
// SpatioTemporalOutageModel:
//   GCN(14->64) -> GCN(64->64)+county_bias -> LSTM(64->128, T=336) -> MLP(128->64->1)
//
// R4:
//  - GCN1 reordered: relu((A.X).W1+b1) -- aggregate 14-dim x (62MB/chunk
//    gather) instead of 64-dim x.W1 (285MB).
//  - GCN2: (A.h).W2; h stored f16 (gather halves to 142MB); agg kernels batch
//    4 timesteps per wave (CSR loads amortized, 4 independent gather streams).
//  - LSTM: launch_bounds(512,1) -- R3's (512,2) capped VGPR at 112 and SPILLED
//    the 96-VGPR weight fragments to scratch (the 130us mystery). Grid is 203
//    blocks <= 256 CUs so 1 block/CU is free. Gate tiles remapped: wave w owns
//    gates {i,f,g,o} x units [16w,16w+16) -> elementwise entirely in MFMA
//    accumulators (c,h in VGPRs), no gate LDS round-trip, ONE barrier/step.
//    x-fragments straight from global with next-t prefetch; weights pre-packed
//    in fragment order by k_wprep (24 coalesced b128 loads per block).
// ---------------------------------------------------------------------------

#define T_DIM 336
#define N_DIM 3233
#define E_DIM 20000
#define FEAT  14
#define D_DIM 64
#define H_DIM 128
#define ET    (E_DIM + N_DIM)     // edges + self loops = 23233

typedef _Float16 f16;
typedef _Float16 half8_t __attribute__((ext_vector_type(8)));
typedef float float4_t __attribute__((ext_vector_type(4)));

__device__ __forceinline__ float sigf(float x) {
    return 1.f / (1.f + exp2f(-1.4426950408889634f * x));
}
__device__ __forceinline__ float tanhfast(float x) {
    return 1.f - 2.f / (1.f + exp2f(2.8853900817779268f * x));
}

// ---------------- CSR build (deterministic) ----------------

__global__ void k_init(int* cnt, int* fill) {
    int i = blockIdx.x * 256 + threadIdx.x;
    if (i < N_DIM) { cnt[i] = 0; fill[i] = 0; }
}

__global__ void k_cnt(const int* __restrict__ ei, int* cnt) {
    int e = blockIdx.x * 256 + threadIdx.x;
    if (e < E_DIM) atomicAdd(&cnt[ei[E_DIM + e]], 1);
}

__global__ void k_scan(const int* __restrict__ cnt, int* __restrict__ rowp) {
    __shared__ int csum[1024];
    int tid = threadIdx.x;
    int base = tid * 4;
    int v[4];
    int s = 0;
    #pragma unroll
    for (int m = 0; m < 4; m++) {
        int idx = base + m;
        int len = (idx < N_DIM) ? (cnt[idx] + 1) : 0;
        v[m] = s; s += len;
    }
    csum[tid] = s;
    __syncthreads();
    for (int off = 1; off < 1024; off <<= 1) {
        int t2 = (tid >= off) ? csum[tid - off] : 0;
        __syncthreads();
        csum[tid] += t2;
        __syncthreads();
    }
    int pre = (tid > 0) ? csum[tid - 1] : 0;
    #pragma unroll
    for (int m = 0; m < 4; m++) {
        int idx = base + m;
        if (idx <= N_DIM) rowp[idx] = pre + v[m];
    }
}

__global__ void k_fill(const int* __restrict__ ei, const int* __restrict__ rowp,
                       int* fill, int* __restrict__ eid) {
    int e = blockIdx.x * 256 + threadIdx.x;
    if (e < ET) {
        int d = (e < E_DIM) ? ei[E_DIM + e] : (e - E_DIM);
        int p = rowp[d] + atomicAdd(&fill[d], 1);
        eid[p] = e;
    }
}

__global__ void k_sortdeg(const float* __restrict__ ew, const int* __restrict__ rowp,
                          int* __restrict__ eid, float* __restrict__ dis) {
    int n = blockIdx.x * 256 + threadIdx.x;
    if (n >= N_DIM) return;
    int p0 = rowp[n], p1 = rowp[n + 1];
    for (int i = p0 + 1; i < p1; i++) {
        int key = eid[i];
        int j = i - 1;
        while (j >= p0 && eid[j] > key) { eid[j + 1] = eid[j]; j--; }
        eid[j + 1] = key;
    }
    float deg = 0.f;
    for (int p = p0; p < p1; p++) {
        int e = eid[p];
        deg += (e < E_DIM) ? ew[e] : 1.0f;
    }
    dis[n] = rsqrtf(deg);
}

__global__ void k_csrmat(const int* __restrict__ ei, const float* __restrict__ ew,
                         const float* __restrict__ dis, const int* __restrict__ rowp,
                         const int* __restrict__ eid, int* __restrict__ csrc,
                         float* __restrict__ cnrm) {
    int n = blockIdx.x * 256 + threadIdx.x;
    if (n >= N_DIM) return;
    float dn = dis[n];
    int p0 = rowp[n], p1 = rowp[n + 1];
    for (int p = p0; p < p1; p++) {
        int e = eid[p];
        int s; float w;
        if (e < E_DIM) { s = ei[e]; w = ew[e]; }
        else           { s = e - E_DIM; w = 1.0f; }
        csrc[p] = s;
        cnrm[p] = dis[s] * w * dn;
    }
}

// ---------------- LSTM weight pre-pack into MFMA B-fragment order ----------------
// wfbuf[(((wv*4+ct)*6+ks)*64 + lane)*8 + j] = W[g][k], g=128ct+16wv+r, k=32ks'+8q+j
__global__ void k_wprep(const float* __restrict__ Wih, const float* __restrict__ Whh,
                        f16* __restrict__ wfbuf) {
    int idx = blockIdx.x * 256 + threadIdx.x;   // 0 .. 8*4*6*64-1
    if (idx >= 8 * 4 * 6 * 64) return;
    int lane = idx & 63;
    int ks = (idx >> 6) % 6;
    int ct = ((idx >> 6) / 6) & 3;
    int wv = (idx >> 6) / 24;
    int q = lane >> 4, r = lane & 15;
    int g = 128 * ct + 16 * wv + r;
    const float* src = (ks < 2) ? (Wih + (long)g * 64 + 32 * ks + 8 * q)
                                : (Whh + (long)g * 128 + 32 * (ks - 2) + 8 * q);
    f16* dst = wfbuf + (long)idx * 8;
    #pragma unroll
    for (int j = 0; j < 8; j++) dst[j] = (f16)src[j];
}

// ---------------- GCN1a: aggX = A.x  (14-dim gather, 4 timesteps/wave) ----------------
__global__ void k_aggx(const float* __restrict__ x, const int* __restrict__ rowp,
                       const int* __restrict__ csrc, const float* __restrict__ cnrm,
                       float* __restrict__ aggX, int tc) {
    int lane = threadIdx.x & 63;
    long wid = ((long)blockIdx.x * 256 + threadIdx.x) >> 6;
    int ntg = (tc + 3) >> 2;
    if (wid >= (long)N_DIM * ntg) return;
    int n = (int)(wid % N_DIM);
    int tg = (int)(wid / N_DIM);
    int j = lane >> 4, d = lane & 15;
    int tj = 4 * tg + j;
    bool live = (d < FEAT) && (tj < tc);
    float acc = 0.f;
    int p0 = rowp[n], p1 = rowp[n + 1];
    for (int p = p0; p < p1; p++) {
        int s = csrc[p];
        float w = cnrm[p];
        if (live) acc += w * x[((long)tj * N_DIM + s) * FEAT + d];
    }
    if (tj < tc) aggX[((long)tj * N_DIM + n) * 16 + d] = acc;
}

// ---------------- GCN1b: h = relu(aggX.W1 + b1) -> f16 ----------------
__global__ void k_tr1(const float* __restrict__ aggX, const float* __restrict__ W1,
                      const float* __restrict__ b1, f16* __restrict__ h, long rows) {
    int lane = threadIdx.x & 63;
    long wid = ((long)blockIdx.x * 256 + threadIdx.x) >> 6;
    float wc[FEAT];
    #pragma unroll
    for (int k = 0; k < FEAT; k++) wc[k] = W1[k * 64 + lane];
    float bb = b1[lane];
    long r0 = wid * 2;
    if (r0 >= rows) return;
    long r1 = r0 + 1;
    bool has1 = (r1 < rows);
    const float* p0 = aggX + r0 * 16;
    const float* p1 = aggX + (has1 ? r1 : r0) * 16;
    float a0 = bb, a1 = bb;
    #pragma unroll
    for (int k = 0; k < FEAT; k++) { a0 += p0[k] * wc[k]; a1 += p1[k] * wc[k]; }
    h[r0 * 64 + lane] = (f16)fmaxf(a0, 0.f);
    if (has1) h[r1 * 64 + lane] = (f16)fmaxf(a1, 0.f);
}

// ---------------- GCN2a: ah = A.h  (f16 gather, 4 timesteps/wave) ----------------
__global__ void k_agg2(const f16* __restrict__ h, const int* __restrict__ rowp,
                       const int* __restrict__ csrc, const float* __restrict__ cnrm,
                       float* __restrict__ ah, int tc) {
    int lane = threadIdx.x & 63;
    long wid = ((long)blockIdx.x * 256 + threadIdx.x) >> 6;
    int ntg = (tc + 3) >> 2;
    if (wid >= (long)N_DIM * ntg) return;
    int n = (int)(wid % N_DIM);
    int tg = (int)(wid / N_DIM);
    int tbase = 4 * tg;
    float acc0 = 0.f, acc1 = 0.f, acc2 = 0.f, acc3 = 0.f;
    int p0 = rowp[n], p1 = rowp[n + 1];
    for (int p = p0; p < p1; p++) {
        int s = csrc[p];
        float w = cnrm[p];
        const f16* base = h + ((long)tbase * N_DIM + s) * 64 + lane;
        acc0 += w * (float)base[0];
        if (tbase + 1 < tc) acc1 += w * (float)base[(long)N_DIM * 64];
        if (tbase + 2 < tc) acc2 += w * (float)base[(long)N_DIM * 128];
        if (tbase + 3 < tc) acc3 += w * (float)base[(long)N_DIM * 192];
    }
    float* dst = ah + ((long)tbase * N_DIM + n) * 64 + lane;
    dst[0] = acc0;
    if (tbase + 1 < tc) dst[(long)N_DIM * 64] = acc1;
    if (tbase + 2 < tc) dst[(long)N_DIM * 128] = acc2;
    if (tbase + 3 < tc) dst[(long)N_DIM * 192] = acc3;
}

// ---------------- GCN2b: emb = ah.W2 + b2 + county -> f16 ----------------
__global__ void k_tr2(const float* __restrict__ ah, const float* __restrict__ W2,
                      const float* __restrict__ b2, const float* __restrict__ county,
                      f16* __restrict__ emb, long rows) {
    int lane = threadIdx.x & 63;
    long wid = ((long)blockIdx.x * 256 + threadIdx.x) >> 6;
    float wc[D_DIM];
    #pragma unroll
    for (int k = 0; k < D_DIM; k++) wc[k] = W2[k * 64 + lane];
    float bb = b2[lane];
    long r0 = wid * 2;
    if (r0 >= rows) return;
    long r1 = r0 + 1;
    bool has1 = (r1 < rows);
    int n0 = (int)(r0 % N_DIM), n1 = (int)(r1 % N_DIM);
    const float* p0 = ah + r0 * 64;
    const float* p1 = ah + (has1 ? r1 : r0) * 64;
    float a0 = bb + county[(long)n0 * 64 + lane];
    float a1 = bb + county[(long)(has1 ? n1 : n0) * 64 + lane];
    #pragma unroll
    for (int k = 0; k < D_DIM; k++) { a0 += p0[k] * wc[k]; a1 += p1[k] * wc[k]; }
    emb[r0 * 64 + lane] = (f16)a0;
    if (has1) emb[r1 * 64 + lane] = (f16)a1;
}

// ---------------- LSTM chunk (f16 MFMA, in-register gates) + MLP head ----------------
// Wave wv owns gate-types ct={i,f,g,o} x units [16wv,16wv+16). Thread (wv,q,r):
// nodes 4q+reg, unit u=16wv+r -> all 4 gates of (node,u) live in acc[ct][reg].
__global__ __launch_bounds__(512, 1) void k_lstm(
    const f16* __restrict__ emb, const f16* __restrict__ wfbuf,
    const float* __restrict__ bih, const float* __restrict__ bhh,
    const float* __restrict__ Wm1, const float* __restrict__ bm1,
    const float* __restrict__ Wm2, const float* __restrict__ bm2,
    float* __restrict__ Hst, float* __restrict__ Cst,
    int tc, int do_init, int do_head, float* __restrict__ out) {
    __shared__ __align__(16) f16   xh[2][16][136];   // h (128 units + pad), double-buffered
    __shared__ __align__(16) float hd[16][132];      // head scratch
    __shared__ __align__(16) float zs[16][64];

    int tid = threadIdx.x;
    int wv = tid >> 6, lane = tid & 63, q = lane >> 4, r = lane & 15;
    int nb = blockIdx.x * 16;
    int cnt = min(16, N_DIM - nb);
    int u = 16 * wv + r;

    // prepped weight fragments: 24 coalesced b128 loads
    half8_t wf[4][6];
    #pragma unroll
    for (int ct = 0; ct < 4; ct++)
        #pragma unroll
        for (int ks = 0; ks < 6; ks++)
            wf[ct][ks] = *(const half8_t*)&wfbuf[(long)((((wv * 4 + ct) * 6 + ks) << 6) + lane) * 8];
    float bias[4];
    #pragma unroll
    for (int ct = 0; ct < 4; ct++) bias[ct] = bih[128 * ct + u] + bhh[128 * ct + u];

    // state in VGPRs
    float cv[4], hvv[4];
    #pragma unroll
    for (int reg = 0; reg < 4; reg++) {
        int node = 4 * q + reg;
        bool live = (!do_init) && (node < cnt);
        hvv[reg] = live ? Hst[(long)(nb + node) * H_DIM + u] : 0.f;
        cv[reg]  = live ? Cst[(long)(nb + node) * H_DIM + u] : 0.f;
        xh[0][node][u] = (f16)hvv[reg];
    }

    int xrow = nb + r; if (xrow >= N_DIM) xrow = N_DIM - 1;
    half8_t xa = *(const half8_t*)(emb + (long)xrow * 64 + 8 * q);
    half8_t xb = *(const half8_t*)(emb + (long)xrow * 64 + 32 + 8 * q);

    int buf = 0;
    __syncthreads();

    for (int t = 0; t < tc; t++) {
        half8_t a2 = *(const half8_t*)&xh[buf][r][8 * q];
        half8_t a3 = *(const half8_t*)&xh[buf][r][32 + 8 * q];
        half8_t a4 = *(const half8_t*)&xh[buf][r][64 + 8 * q];
        half8_t a5 = *(const half8_t*)&xh[buf][r][96 + 8 * q];

        float4_t acc[4];
        #pragma unroll
        for (int ct = 0; ct < 4; ct++) {
            acc[ct][0] = bias[ct]; acc[ct][1] = bias[ct];
            acc[ct][2] = bias[ct]; acc[ct][3] = bias[ct];
        }
        #pragma unroll
        for (int ct = 0; ct < 4; ct++) acc[ct] = __builtin_amdgcn_mfma_f32_16x16x32_f16(xa, wf[ct][0], acc[ct], 0, 0, 0);
        #pragma unroll
        for (int ct = 0; ct < 4; ct++) acc[ct] = __builtin_amdgcn_mfma_f32_16x16x32_f16(xb, wf[ct][1], acc[ct], 0, 0, 0);
        #pragma unroll
        for (int ct = 0; ct < 4; ct++) acc[ct] = __builtin_amdgcn_mfma_f32_16x16x32_f16(a2, wf[ct][2], acc[ct], 0, 0, 0);
        #pragma unroll
        for (int ct = 0; ct < 4; ct++) acc[ct] = __builtin_amdgcn_mfma_f32_16x16x32_f16(a3, wf[ct][3], acc[ct], 0, 0, 0);
        #pragma unroll
        for (int ct = 0; ct < 4; ct++) acc[ct] = __builtin_amdgcn_mfma_f32_16x16x32_f16(a4, wf[ct][4], acc[ct], 0, 0, 0);
        #pragma unroll
        for (int ct = 0; ct < 4; ct++) acc[ct] = __builtin_amdgcn_mfma_f32_16x16x32_f16(a5, wf[ct][5], acc[ct], 0, 0, 0);

        // elementwise in-register: acc[ct][reg] = gate ct of (node 4q+reg, unit u)
        #pragma unroll
        for (int reg = 0; reg < 4; reg++) {
            float gi = acc[0][reg], gf = acc[1][reg], gg = acc[2][reg], go = acc[3][reg];
            float c = sigf(gf) * cv[reg] + sigf(gi) * tanhfast(gg);
            float hh = sigf(go) * tanhfast(c);
            cv[reg] = c; hvv[reg] = hh;
            xh[buf ^ 1][4 * q + reg][u] = (f16)hh;
        }
        // prefetch next x before the barrier
        int tn = (t + 1 < tc) ? t + 1 : t;
        const f16* xp = emb + ((long)tn * N_DIM + xrow) * 64;
        xa = *(const half8_t*)(xp + 8 * q);
        xb = *(const half8_t*)(xp + 32 + 8 * q);
        __syncthreads();
        buf ^= 1;
    }

    #pragma unroll
    for (int reg = 0; reg < 4; reg++) {
        int node = 4 * q + reg;
        if (node < cnt) {
            Hst[(long)(nb + node) * H_DIM + u] = hvv[reg];
            Cst[(long)(nb + node) * H_DIM + u] = cv[reg];
        }
    }
    if (!do_head) return;

    #pragma unroll
    for (int reg = 0; reg < 4; reg++) hd[4 * q + reg][u] = hvv[reg];
    __syncthreads();

    for (int i = tid; i < 16 * 64; i += 512) {
        int n = i >> 6, m = i & 63;
        float a = bm1[m];
        #pragma unroll 8
        for (int k = 0; k < H_DIM; k++) a += hd[n][k] * Wm1[k * 64 + m];
        zs[n][m] = fmaxf(a, 0.f);
    }
    __syncthreads();
    if (tid < cnt) {
        float a = bm2[0];
        #pragma unroll 8
        for (int m = 0; m < 64; m++) a += zs[tid][m] * Wm2[m];
        out[nb + tid] = a;
    }
}

// ---------------------------------------------------------------------------

extern "C" void kernel_launch(void* const* d_in, const int* in_sizes, int n_in,
                              void* d_out, int out_size, void* d_ws, size_t ws_size,
                              hipStream_t stream) {
    const float* x   = (const float*)d_in[0];
    const int*   ei  = (const int*)d_in[1];
    const float* ew  = (const float*)d_in[2];
    const float* W1  = (const float*)d_in[3];
    const float* b1  = (const float*)d_in[4];
    const float* W2  = (const float*)d_in[5];
    const float* b2  = (const float*)d_in[6];
    const float* cb  = (const float*)d_in[7];
    const float* Wih = (const float*)d_in[8];
    const float* Whh = (const float*)d_in[9];
    const float* bih = (const float*)d_in[10];
    const float* bhh = (const float*)d_in[11];
    const float* Wm1 = (const float*)d_in[12];
    const float* bm1 = (const float*)d_in[13];
    const float* Wm2 = (const float*)d_in[14];
    const float* bm2 = (const float*)d_in[15];
    float* out = (float*)d_out;
    (void)in_sizes; (void)n_in; (void)out_size;

    char* ws = (char*)d_ws;
    size_t off = 0;
    auto alloc = [&](size_t bytes) -> char* {
        char* p = ws + off;
        off = (off + bytes + 255) & ~(size_t)255;
        return p;
    };
    float* dis   = (float*)alloc(N_DIM * 4);
    int*   cnt   = (int*)alloc(N_DIM * 4);
    int*   fill  = (int*)alloc(N_DIM * 4);
    int*   rowp  = (int*)alloc((N_DIM + 1) * 4);
    int*   eid   = (int*)alloc(ET * 4);
    int*   csrc  = (int*)alloc(ET * 4);
    float* cnrm  = (float*)alloc(ET * 4);
    float* Hst   = (float*)alloc((size_t)N_DIM * H_DIM * 4);
    float* Cst   = (float*)alloc((size_t)N_DIM * H_DIM * 4);
    f16*   wfbuf = (f16*)alloc((size_t)8 * 4 * 6 * 64 * 8 * 2);

    // largest Tc dividing 336 whose chunk buffers (rows*512B) fit
    const int cand[] = {336, 168, 112, 84, 56, 48, 28, 16, 8, 4};
    int Tc = 4;
    for (int i = 0; i < 10; i++) {
        size_t need = off + (size_t)cand[i] * N_DIM * 512 + 4096;
        if (need <= ws_size) { Tc = cand[i]; break; }
    }
    long rows = (long)Tc * N_DIM;
    float* bufR1 = (float*)alloc(rows * 128);   // aggX (rows*64B prefix) / emb f16 alias
    f16*   hbuf  = (f16*)alloc(rows * 128);     // h f16
    float* ahbuf = (float*)alloc(rows * 256);   // ah f32
    float* aggX  = bufR1;
    f16*   embb  = (f16*)bufR1;

    // --- one-time: CSR build + LSTM weight pre-pack ---
    k_init<<<(N_DIM + 255) / 256, 256, 0, stream>>>(cnt, fill);
    k_cnt<<<(E_DIM + 255) / 256, 256, 0, stream>>>(ei, cnt);
    k_scan<<<1, 1024, 0, stream>>>(cnt, rowp);
    k_fill<<<(ET + 255) / 256, 256, 0, stream>>>(ei, rowp, fill, eid);
    k_sortdeg<<<(N_DIM + 255) / 256, 256, 0, stream>>>(ew, rowp, eid, dis);
    k_csrmat<<<(N_DIM + 255) / 256, 256, 0, stream>>>(ei, ew, dis, rowp, eid, csrc, cnrm);
    k_wprep<<<48, 256, 0, stream>>>(Wih, Whh, wfbuf);

    int ntg = (Tc + 3) >> 2;
    long aggWaves = (long)N_DIM * ntg;
    int aggBlocks = (int)((aggWaves + 3) / 4);
    int trBlocks  = (int)(((rows + 1) / 2 + 3) / 4);
    int lblocks   = (N_DIM + 15) / 16;
    int nChunks   = T_DIM / Tc;

    for (int c = 0; c < nChunks; c++) {
        long t0 = (long)c * Tc;
        k_aggx<<<aggBlocks, 256, 0, stream>>>(x + t0 * N_DIM * FEAT, rowp, csrc, cnrm, aggX, Tc);
        k_tr1<<<trBlocks, 256, 0, stream>>>(aggX, W1, b1, hbuf, rows);
        k_agg2<<<aggBlocks, 256, 0, stream>>>(hbuf, rowp, csrc, cnrm, ahbuf, Tc);
        k_tr2<<<trBlocks, 256, 0, stream>>>(ahbuf, W2, b2, cb, embb, rows);
        k_lstm<<<lblocks, 512, 0, stream>>>(embb, wfbuf, bih, bhh, Wm1, bm1, Wm2, bm2,
                                            Hst, Cst, Tc, c == 0 ? 1 : 0,
                                            c == nChunks - 1 ? 1 : 0, out);
    }
}

// Round 5
// 1525.154 us; speedup vs baseline: 4.3492x; 1.4519x over previous
//
#include <hip/hip_runtime.h>
#include <math.h>

// ---------------------------------------------------------------------------
// SpatioTemporalOutageModel:
//   GCN(14->64) -> GCN(64->64)+county_bias -> LSTM(64->128, T=336) -> MLP(128->64->1)
//
// R5:
//  - k_tr2 ELIMINATED by algebra: gates = emb@Wih^T with emb=(A.h)@W2+b2+county
//    => fold W' = W2@Wih^T (64x512, packed into MFMA B-fragments once) and
//    gbias[n][g] = (b2+county[n])@Wih[g,:] + bih[g]+bhh[g] (N x 512, once).
//    LSTM consumes ah (=A.h, f16) directly; acc init from per-node gbias.
//    R4 profile: k_tr2 was 3 x 260us (35%) -- broadcast-load latency-bound.
//  - k_agg2 writes f16 (ah buffer halves; was the 92MB fp32 round-trip).
//  - Per-row chunk footprint 512->320B => Tc can reach 168.
//  - LSTM (from R4): launch_bounds(512,1); wave wv owns gates {i,f,g,o} x
//    units [16wv,16wv+16); elementwise in MFMA accumulators; one barrier/step.
// ---------------------------------------------------------------------------

#define T_DIM 336
#define N_DIM 3233
#define E_DIM 20000
#define FEAT  14
#define D_DIM 64
#define H_DIM 128
#define ET    (E_DIM + N_DIM)     // edges + self loops = 23233

typedef _Float16 f16;
typedef _Float16 half8_t __attribute__((ext_vector_type(8)));
typedef float float4_t __attribute__((ext_vector_type(4)));

__device__ __forceinline__ float sigf(float x) {
    return 1.f / (1.f + exp2f(-1.4426950408889634f * x));
}
__device__ __forceinline__ float tanhfast(float x) {
    return 1.f - 2.f / (1.f + exp2f(2.8853900817779268f * x));
}

// ---------------- CSR build (deterministic) ----------------

__global__ void k_init(int* cnt, int* fill) {
    int i = blockIdx.x * 256 + threadIdx.x;
    if (i < N_DIM) { cnt[i] = 0; fill[i] = 0; }
}

__global__ void k_cnt(const int* __restrict__ ei, int* cnt) {
    int e = blockIdx.x * 256 + threadIdx.x;
    if (e < E_DIM) atomicAdd(&cnt[ei[E_DIM + e]], 1);
}

__global__ void k_scan(const int* __restrict__ cnt, int* __restrict__ rowp) {
    __shared__ int csum[1024];
    int tid = threadIdx.x;
    int base = tid * 4;
    int v[4];
    int s = 0;
    #pragma unroll
    for (int m = 0; m < 4; m++) {
        int idx = base + m;
        int len = (idx < N_DIM) ? (cnt[idx] + 1) : 0;
        v[m] = s; s += len;
    }
    csum[tid] = s;
    __syncthreads();
    for (int off = 1; off < 1024; off <<= 1) {
        int t2 = (tid >= off) ? csum[tid - off] : 0;
        __syncthreads();
        csum[tid] += t2;
        __syncthreads();
    }
    int pre = (tid > 0) ? csum[tid - 1] : 0;
    #pragma unroll
    for (int m = 0; m < 4; m++) {
        int idx = base + m;
        if (idx <= N_DIM) rowp[idx] = pre + v[m];
    }
}

__global__ void k_fill(const int* __restrict__ ei, const int* __restrict__ rowp,
                       int* fill, int* __restrict__ eid) {
    int e = blockIdx.x * 256 + threadIdx.x;
    if (e < ET) {
        int d = (e < E_DIM) ? ei[E_DIM + e] : (e - E_DIM);
        int p = rowp[d] + atomicAdd(&fill[d], 1);
        eid[p] = e;
    }
}

__global__ void k_sortdeg(const float* __restrict__ ew, const int* __restrict__ rowp,
                          int* __restrict__ eid, float* __restrict__ dis) {
    int n = blockIdx.x * 256 + threadIdx.x;
    if (n >= N_DIM) return;
    int p0 = rowp[n], p1 = rowp[n + 1];
    for (int i = p0 + 1; i < p1; i++) {
        int key = eid[i];
        int j = i - 1;
        while (j >= p0 && eid[j] > key) { eid[j + 1] = eid[j]; j--; }
        eid[j + 1] = key;
    }
    float deg = 0.f;
    for (int p = p0; p < p1; p++) {
        int e = eid[p];
        deg += (e < E_DIM) ? ew[e] : 1.0f;
    }
    dis[n] = rsqrtf(deg);
}

__global__ void k_csrmat(const int* __restrict__ ei, const float* __restrict__ ew,
                         const float* __restrict__ dis, const int* __restrict__ rowp,
                         const int* __restrict__ eid, int* __restrict__ csrc,
                         float* __restrict__ cnrm) {
    int n = blockIdx.x * 256 + threadIdx.x;
    if (n >= N_DIM) return;
    float dn = dis[n];
    int p0 = rowp[n], p1 = rowp[n + 1];
    for (int p = p0; p < p1; p++) {
        int e = eid[p];
        int s; float w;
        if (e < E_DIM) { s = ei[e]; w = ew[e]; }
        else           { s = e - E_DIM; w = 1.0f; }
        csrc[p] = s;
        cnrm[p] = dis[s] * w * dn;
    }
}

// ---------------- weight prep: fold W2 into Wih, pack B-fragments ----------------
// fragment idx = ((wv*4+ct)*6+ks)*64 + lane; gate g = 128ct+16wv+r.
// ks 0-1: W'[k][g] = sum_d W2[k][d]*Wih[g][d]   (k = 32ks+8q+j, ah-space)
// ks 2-5: Whh[g][k-64]                          (k-64 = 32(ks-2)+8q+j)
__global__ void k_wprep(const float* __restrict__ W2, const float* __restrict__ Wih,
                        const float* __restrict__ Whh, f16* __restrict__ wfbuf) {
    int idx = blockIdx.x * 256 + threadIdx.x;
    if (idx >= 8 * 4 * 6 * 64) return;
    int lane = idx & 63;
    int ks = (idx >> 6) % 6;
    int ct = ((idx >> 6) / 6) & 3;
    int wv = (idx >> 6) / 24;
    int q = lane >> 4, r = lane & 15;
    int g = 128 * ct + 16 * wv + r;
    f16* dst = wfbuf + (long)idx * 8;
    if (ks < 2) {
        const float* wir = Wih + (long)g * 64;
        #pragma unroll
        for (int j = 0; j < 8; j++) {
            int k = 32 * ks + 8 * q + j;
            const float* w2r = W2 + (long)k * 64;
            float s = 0.f;
            #pragma unroll 16
            for (int d = 0; d < 64; d++) s += w2r[d] * wir[d];
            dst[j] = (f16)s;
        }
    } else {
        const float* src = Whh + (long)g * 128 + 32 * (ks - 2) + 8 * q;
        #pragma unroll
        for (int j = 0; j < 8; j++) dst[j] = (f16)src[j];
    }
}

// gbias[n][g] = bih[g]+bhh[g] + sum_d (b2[d]+county[n][d])*Wih[g][d]
__global__ void k_gbias(const float* __restrict__ county, const float* __restrict__ b2,
                        const float* __restrict__ Wih, const float* __restrict__ bih,
                        const float* __restrict__ bhh, float* __restrict__ gbias) {
    long id = (long)blockIdx.x * 256 + threadIdx.x;
    if (id >= (long)N_DIM * 512) return;
    int n = (int)(id >> 9), g = (int)(id & 511);
    const float* wir = Wih + (long)g * 64;
    const float* cn = county + (long)n * 64;
    float s = bih[g] + bhh[g];
    #pragma unroll 16
    for (int d = 0; d < 64; d++) s += (b2[d] + cn[d]) * wir[d];
    gbias[id] = s;
}

// ---------------- GCN1a: aggX = A.x  (14-dim gather, 4 timesteps/wave) ----------------
__global__ void k_aggx(const float* __restrict__ x, const int* __restrict__ rowp,
                       const int* __restrict__ csrc, const float* __restrict__ cnrm,
                       float* __restrict__ aggX, int tc) {
    int lane = threadIdx.x & 63;
    long wid = ((long)blockIdx.x * 256 + threadIdx.x) >> 6;
    int ntg = (tc + 3) >> 2;
    if (wid >= (long)N_DIM * ntg) return;
    int n = (int)(wid % N_DIM);
    int tg = (int)(wid / N_DIM);
    int j = lane >> 4, d = lane & 15;
    int tj = 4 * tg + j;
    bool live = (d < FEAT) && (tj < tc);
    float acc = 0.f;
    int p0 = rowp[n], p1 = rowp[n + 1];
    for (int p = p0; p < p1; p++) {
        int s = csrc[p];
        float w = cnrm[p];
        if (live) acc += w * x[((long)tj * N_DIM + s) * FEAT + d];
    }
    if (tj < tc) aggX[((long)tj * N_DIM + n) * 16 + d] = acc;
}

// ---------------- GCN1b: h = relu(aggX.W1 + b1) -> f16 ----------------
__global__ void k_tr1(const float* __restrict__ aggX, const float* __restrict__ W1,
                      const float* __restrict__ b1, f16* __restrict__ h, long rows) {
    int lane = threadIdx.x & 63;
    long wid = ((long)blockIdx.x * 256 + threadIdx.x) >> 6;
    float wc[FEAT];
    #pragma unroll
    for (int k = 0; k < FEAT; k++) wc[k] = W1[k * 64 + lane];
    float bb = b1[lane];
    long r0 = wid * 2;
    if (r0 >= rows) return;
    long r1 = r0 + 1;
    bool has1 = (r1 < rows);
    const float* p0 = aggX + r0 * 16;
    const float* p1 = aggX + (has1 ? r1 : r0) * 16;
    float a0 = bb, a1 = bb;
    #pragma unroll
    for (int k = 0; k < FEAT; k++) { a0 += p0[k] * wc[k]; a1 += p1[k] * wc[k]; }
    h[r0 * 64 + lane] = (f16)fmaxf(a0, 0.f);
    if (has1) h[r1 * 64 + lane] = (f16)fmaxf(a1, 0.f);
}

// ---------------- GCN2a: ah = A.h  (f16 gather -> f16 out, 4 timesteps/wave) ----------------
__global__ void k_agg2(const f16* __restrict__ h, const int* __restrict__ rowp,
                       const int* __restrict__ csrc, const float* __restrict__ cnrm,
                       f16* __restrict__ ah, int tc) {
    int lane = threadIdx.x & 63;
    long wid = ((long)blockIdx.x * 256 + threadIdx.x) >> 6;
    int ntg = (tc + 3) >> 2;
    if (wid >= (long)N_DIM * ntg) return;
    int n = (int)(wid % N_DIM);
    int tg = (int)(wid / N_DIM);
    int tbase = 4 * tg;
    float acc0 = 0.f, acc1 = 0.f, acc2 = 0.f, acc3 = 0.f;
    int p0 = rowp[n], p1 = rowp[n + 1];
    for (int p = p0; p < p1; p++) {
        int s = csrc[p];
        float w = cnrm[p];
        const f16* base = h + ((long)tbase * N_DIM + s) * 64 + lane;
        acc0 += w * (float)base[0];
        if (tbase + 1 < tc) acc1 += w * (float)base[(long)N_DIM * 64];
        if (tbase + 2 < tc) acc2 += w * (float)base[(long)N_DIM * 128];
        if (tbase + 3 < tc) acc3 += w * (float)base[(long)N_DIM * 192];
    }
    f16* dst = ah + ((long)tbase * N_DIM + n) * 64 + lane;
    dst[0] = (f16)acc0;
    if (tbase + 1 < tc) dst[(long)N_DIM * 64] = (f16)acc1;
    if (tbase + 2 < tc) dst[(long)N_DIM * 128] = (f16)acc2;
    if (tbase + 3 < tc) dst[(long)N_DIM * 192] = (f16)acc3;
}

// ---------------- LSTM chunk (f16 MFMA, in-register gates) + MLP head ----------------
// Wave wv owns gate-types ct={i,f,g,o} x units [16wv,16wv+16). Thread (wv,q,r):
// nodes 4q+reg, unit u=16wv+r -> all 4 gates of (node,u) live in acc[ct][reg].
__global__ __launch_bounds__(512, 1) void k_lstm(
    const f16* __restrict__ ah, const f16* __restrict__ wfbuf,
    const float* __restrict__ gbias,
    const float* __restrict__ Wm1, const float* __restrict__ bm1,
    const float* __restrict__ Wm2, const float* __restrict__ bm2,
    float* __restrict__ Hst, float* __restrict__ Cst,
    int tc, int do_init, int do_head, float* __restrict__ out) {
    __shared__ __align__(16) f16   xh[2][16][136];   // h (128 units + pad), double-buffered
    __shared__ __align__(16) float hd[16][132];      // head scratch
    __shared__ __align__(16) float zs[16][64];

    int tid = threadIdx.x;
    int wv = tid >> 6, lane = tid & 63, q = lane >> 4, r = lane & 15;
    int nb = blockIdx.x * 16;
    int cnt = min(16, N_DIM - nb);
    int u = 16 * wv + r;

    // prepped weight fragments: 24 coalesced b128 loads
    half8_t wf[4][6];
    #pragma unroll
    for (int ct = 0; ct < 4; ct++)
        #pragma unroll
        for (int ks = 0; ks < 6; ks++)
            wf[ct][ks] = *(const half8_t*)&wfbuf[(long)((((wv * 4 + ct) * 6 + ks) << 6) + lane) * 8];

    // per-node folded bias (b2+county pushed through Wih, plus bih+bhh)
    float gb[4][4];
    #pragma unroll
    for (int reg = 0; reg < 4; reg++) {
        int node = 4 * q + reg;
        int gn = nb + node; if (gn >= N_DIM) gn = N_DIM - 1;
        #pragma unroll
        for (int ct = 0; ct < 4; ct++)
            gb[ct][reg] = gbias[(long)gn * 512 + 128 * ct + u];
    }

    // state in VGPRs
    float cv[4], hvv[4];
    #pragma unroll
    for (int reg = 0; reg < 4; reg++) {
        int node = 4 * q + reg;
        bool live = (!do_init) && (node < cnt);
        hvv[reg] = live ? Hst[(long)(nb + node) * H_DIM + u] : 0.f;
        cv[reg]  = live ? Cst[(long)(nb + node) * H_DIM + u] : 0.f;
        xh[0][node][u] = (f16)hvv[reg];
    }

    int xrow = nb + r; if (xrow >= N_DIM) xrow = N_DIM - 1;
    half8_t xa = *(const half8_t*)(ah + (long)xrow * 64 + 8 * q);
    half8_t xb = *(const half8_t*)(ah + (long)xrow * 64 + 32 + 8 * q);

    int buf = 0;
    __syncthreads();

    for (int t = 0; t < tc; t++) {
        half8_t a2 = *(const half8_t*)&xh[buf][r][8 * q];
        half8_t a3 = *(const half8_t*)&xh[buf][r][32 + 8 * q];
        half8_t a4 = *(const half8_t*)&xh[buf][r][64 + 8 * q];
        half8_t a5 = *(const half8_t*)&xh[buf][r][96 + 8 * q];

        float4_t acc[4];
        #pragma unroll
        for (int ct = 0; ct < 4; ct++) {
            acc[ct][0] = gb[ct][0]; acc[ct][1] = gb[ct][1];
            acc[ct][2] = gb[ct][2]; acc[ct][3] = gb[ct][3];
        }
        #pragma unroll
        for (int ct = 0; ct < 4; ct++) acc[ct] = __builtin_amdgcn_mfma_f32_16x16x32_f16(xa, wf[ct][0], acc[ct], 0, 0, 0);
        #pragma unroll
        for (int ct = 0; ct < 4; ct++) acc[ct] = __builtin_amdgcn_mfma_f32_16x16x32_f16(xb, wf[ct][1], acc[ct], 0, 0, 0);
        #pragma unroll
        for (int ct = 0; ct < 4; ct++) acc[ct] = __builtin_amdgcn_mfma_f32_16x16x32_f16(a2, wf[ct][2], acc[ct], 0, 0, 0);
        #pragma unroll
        for (int ct = 0; ct < 4; ct++) acc[ct] = __builtin_amdgcn_mfma_f32_16x16x32_f16(a3, wf[ct][3], acc[ct], 0, 0, 0);
        #pragma unroll
        for (int ct = 0; ct < 4; ct++) acc[ct] = __builtin_amdgcn_mfma_f32_16x16x32_f16(a4, wf[ct][4], acc[ct], 0, 0, 0);
        #pragma unroll
        for (int ct = 0; ct < 4; ct++) acc[ct] = __builtin_amdgcn_mfma_f32_16x16x32_f16(a5, wf[ct][5], acc[ct], 0, 0, 0);

        // elementwise in-register: acc[ct][reg] = gate ct of (node 4q+reg, unit u)
        #pragma unroll
        for (int reg = 0; reg < 4; reg++) {
            float gi = acc[0][reg], gf = acc[1][reg], gg = acc[2][reg], go = acc[3][reg];
            float c = sigf(gf) * cv[reg] + sigf(gi) * tanhfast(gg);
            float hh = sigf(go) * tanhfast(c);
            cv[reg] = c; hvv[reg] = hh;
            xh[buf ^ 1][4 * q + reg][u] = (f16)hh;
        }
        // prefetch next x before the barrier
        int tn = (t + 1 < tc) ? t + 1 : t;
        const f16* xp = ah + ((long)tn * N_DIM + xrow) * 64;
        xa = *(const half8_t*)(xp + 8 * q);
        xb = *(const half8_t*)(xp + 32 + 8 * q);
        __syncthreads();
        buf ^= 1;
    }

    #pragma unroll
    for (int reg = 0; reg < 4; reg++) {
        int node = 4 * q + reg;
        if (node < cnt) {
            Hst[(long)(nb + node) * H_DIM + u] = hvv[reg];
            Cst[(long)(nb + node) * H_DIM + u] = cv[reg];
        }
    }
    if (!do_head) return;

    #pragma unroll
    for (int reg = 0; reg < 4; reg++) hd[4 * q + reg][u] = hvv[reg];
    __syncthreads();

    for (int i = tid; i < 16 * 64; i += 512) {
        int n = i >> 6, m = i & 63;
        float a = bm1[m];
        #pragma unroll 8
        for (int k = 0; k < H_DIM; k++) a += hd[n][k] * Wm1[k * 64 + m];
        zs[n][m] = fmaxf(a, 0.f);
    }
    __syncthreads();
    if (tid < cnt) {
        float a = bm2[0];
        #pragma unroll 8
        for (int m = 0; m < 64; m++) a += zs[tid][m] * Wm2[m];
        out[nb + tid] = a;
    }
}

// ---------------------------------------------------------------------------

extern "C" void kernel_launch(void* const* d_in, const int* in_sizes, int n_in,
                              void* d_out, int out_size, void* d_ws, size_t ws_size,
                              hipStream_t stream) {
    const float* x   = (const float*)d_in[0];
    const int*   ei  = (const int*)d_in[1];
    const float* ew  = (const float*)d_in[2];
    const float* W1  = (const float*)d_in[3];
    const float* b1  = (const float*)d_in[4];
    const float* W2  = (const float*)d_in[5];
    const float* b2  = (const float*)d_in[6];
    const float* cb  = (const float*)d_in[7];
    const float* Wih = (const float*)d_in[8];
    const float* Whh = (const float*)d_in[9];
    const float* bih = (const float*)d_in[10];
    const float* bhh = (const float*)d_in[11];
    const float* Wm1 = (const float*)d_in[12];
    const float* bm1 = (const float*)d_in[13];
    const float* Wm2 = (const float*)d_in[14];
    const float* bm2 = (const float*)d_in[15];
    float* out = (float*)d_out;
    (void)in_sizes; (void)n_in; (void)out_size;

    char* ws = (char*)d_ws;
    size_t off = 0;
    auto alloc = [&](size_t bytes) -> char* {
        char* p = ws + off;
        off = (off + bytes + 255) & ~(size_t)255;
        return p;
    };
    float* dis   = (float*)alloc(N_DIM * 4);
    int*   cnt   = (int*)alloc(N_DIM * 4);
    int*   fill  = (int*)alloc(N_DIM * 4);
    int*   rowp  = (int*)alloc((N_DIM + 1) * 4);
    int*   eid   = (int*)alloc(ET * 4);
    int*   csrc  = (int*)alloc(ET * 4);
    float* cnrm  = (float*)alloc(ET * 4);
    float* Hst   = (float*)alloc((size_t)N_DIM * H_DIM * 4);
    float* Cst   = (float*)alloc((size_t)N_DIM * H_DIM * 4);
    f16*   wfbuf = (f16*)alloc((size_t)8 * 4 * 6 * 64 * 8 * 2);
    float* gbias = (float*)alloc((size_t)N_DIM * 512 * 4);

    // largest Tc dividing 336 whose chunk buffers (rows*320B) fit
    const int cand[] = {336, 168, 112, 84, 56, 48, 28, 16, 8, 4};
    int Tc = 4;
    for (int i = 0; i < 10; i++) {
        size_t need = off + (size_t)cand[i] * N_DIM * 320 + 4096;
        if (need <= ws_size) { Tc = cand[i]; break; }
    }
    long rows = (long)Tc * N_DIM;
    float* aggX  = (float*)alloc(rows * 64);    // [rows][16] fp32 (14 used)
    f16*   hbuf  = (f16*)alloc(rows * 128);     // h f16
    f16*   ahbuf = (f16*)alloc(rows * 128);     // ah f16

    // --- one-time: CSR build + weight fold/pack + per-node gate bias ---
    k_init<<<(N_DIM + 255) / 256, 256, 0, stream>>>(cnt, fill);
    k_cnt<<<(E_DIM + 255) / 256, 256, 0, stream>>>(ei, cnt);
    k_scan<<<1, 1024, 0, stream>>>(cnt, rowp);
    k_fill<<<(ET + 255) / 256, 256, 0, stream>>>(ei, rowp, fill, eid);
    k_sortdeg<<<(N_DIM + 255) / 256, 256, 0, stream>>>(ew, rowp, eid, dis);
    k_csrmat<<<(N_DIM + 255) / 256, 256, 0, stream>>>(ei, ew, dis, rowp, eid, csrc, cnrm);
    k_wprep<<<48, 256, 0, stream>>>(W2, Wih, Whh, wfbuf);
    k_gbias<<<(int)(((long)N_DIM * 512 + 255) / 256), 256, 0, stream>>>(cb, b2, Wih, bih, bhh, gbias);

    int ntg = (Tc + 3) >> 2;
    long aggWaves = (long)N_DIM * ntg;
    int aggBlocks = (int)((aggWaves + 3) / 4);
    int trBlocks  = (int)(((rows + 1) / 2 + 3) / 4);
    int lblocks   = (N_DIM + 15) / 16;
    int nChunks   = T_DIM / Tc;

    for (int c = 0; c < nChunks; c++) {
        long t0 = (long)c * Tc;
        k_aggx<<<aggBlocks, 256, 0, stream>>>(x + t0 * N_DIM * FEAT, rowp, csrc, cnrm, aggX, Tc);
        k_tr1<<<trBlocks, 256, 0, stream>>>(aggX, W1, b1, hbuf, rows);
        k_agg2<<<aggBlocks, 256, 0, stream>>>(hbuf, rowp, csrc, cnrm, ahbuf, Tc);
        k_lstm<<<lblocks, 512, 0, stream>>>(ahbuf, wfbuf, gbias, Wm1, bm1, Wm2, bm2,
                                            Hst, Cst, Tc, c == 0 ? 1 : 0,
                                            c == nChunks - 1 ? 1 : 0, out);
    }
}

// Round 6
// 1305.166 us; speedup vs baseline: 5.0823x; 1.1686x over previous
//
#include <hip/hip_runtime.h>
#include <math.h>

// ---------------------------------------------------------------------------
// SpatioTemporalOutageModel:
//   GCN(14->64) -> GCN(64->64)+county_bias -> LSTM(64->128, T=336) -> MLP(128->64->1)
//
// R6 (LSTM register-residency fix):
//  - R5 profile: k_lstm = 90% of runtime, VGPR_Count=124 -> compiler STREAMS
//    the 96-VGPR weight fragments from memory every step (rematerialization),
//    ~3.3GB/dispatch through L2. Fix: asm volatile("" : "+v"(x)) pin on all
//    24 weight fragments + 16 gate-bias values (asm outputs can't be
//    rematerialized) + amdgpu_waves_per_eu(2,2) for the full 256-VGPR budget.
//  - IEEE div removed from sigmoid/tanh via __builtin_amdgcn_rcpf (R5 spent
//    ~200 VALU/thread/step in v_div_scale/v_div_fmas sequences).
//  - xa/xb prefetch issued right after their last use -> load latency hidden
//    under MFMA groups 2-5 + elementwise before the barrier's vmcnt(0) drain.
//  - (from R5) k_tr2 folded into LSTM weights: W'=W2@Wih^T, per-node gbias.
// ---------------------------------------------------------------------------

#define T_DIM 336
#define N_DIM 3233
#define E_DIM 20000
#define FEAT  14
#define D_DIM 64
#define H_DIM 128
#define ET    (E_DIM + N_DIM)     // edges + self loops = 23233

typedef _Float16 f16;
typedef _Float16 half8_t __attribute__((ext_vector_type(8)));
typedef float float4_t __attribute__((ext_vector_type(4)));

__device__ __forceinline__ float sigf(float x) {
    return __builtin_amdgcn_rcpf(1.f + exp2f(-1.4426950408889634f * x));
}
__device__ __forceinline__ float tanhfast(float x) {
    return 1.f - 2.f * __builtin_amdgcn_rcpf(1.f + exp2f(2.8853900817779268f * x));
}

// ---------------- CSR build (deterministic) ----------------

__global__ void k_init(int* cnt, int* fill) {
    int i = blockIdx.x * 256 + threadIdx.x;
    if (i < N_DIM) { cnt[i] = 0; fill[i] = 0; }
}

__global__ void k_cnt(const int* __restrict__ ei, int* cnt) {
    int e = blockIdx.x * 256 + threadIdx.x;
    if (e < E_DIM) atomicAdd(&cnt[ei[E_DIM + e]], 1);
}

__global__ void k_scan(const int* __restrict__ cnt, int* __restrict__ rowp) {
    __shared__ int csum[1024];
    int tid = threadIdx.x;
    int base = tid * 4;
    int v[4];
    int s = 0;
    #pragma unroll
    for (int m = 0; m < 4; m++) {
        int idx = base + m;
        int len = (idx < N_DIM) ? (cnt[idx] + 1) : 0;
        v[m] = s; s += len;
    }
    csum[tid] = s;
    __syncthreads();
    for (int off = 1; off < 1024; off <<= 1) {
        int t2 = (tid >= off) ? csum[tid - off] : 0;
        __syncthreads();
        csum[tid] += t2;
        __syncthreads();
    }
    int pre = (tid > 0) ? csum[tid - 1] : 0;
    #pragma unroll
    for (int m = 0; m < 4; m++) {
        int idx = base + m;
        if (idx <= N_DIM) rowp[idx] = pre + v[m];
    }
}

__global__ void k_fill(const int* __restrict__ ei, const int* __restrict__ rowp,
                       int* fill, int* __restrict__ eid) {
    int e = blockIdx.x * 256 + threadIdx.x;
    if (e < ET) {
        int d = (e < E_DIM) ? ei[E_DIM + e] : (e - E_DIM);
        int p = rowp[d] + atomicAdd(&fill[d], 1);
        eid[p] = e;
    }
}

__global__ void k_sortdeg(const float* __restrict__ ew, const int* __restrict__ rowp,
                          int* __restrict__ eid, float* __restrict__ dis) {
    int n = blockIdx.x * 256 + threadIdx.x;
    if (n >= N_DIM) return;
    int p0 = rowp[n], p1 = rowp[n + 1];
    for (int i = p0 + 1; i < p1; i++) {
        int key = eid[i];
        int j = i - 1;
        while (j >= p0 && eid[j] > key) { eid[j + 1] = eid[j]; j--; }
        eid[j + 1] = key;
    }
    float deg = 0.f;
    for (int p = p0; p < p1; p++) {
        int e = eid[p];
        deg += (e < E_DIM) ? ew[e] : 1.0f;
    }
    dis[n] = rsqrtf(deg);
}

__global__ void k_csrmat(const int* __restrict__ ei, const float* __restrict__ ew,
                         const float* __restrict__ dis, const int* __restrict__ rowp,
                         const int* __restrict__ eid, int* __restrict__ csrc,
                         float* __restrict__ cnrm) {
    int n = blockIdx.x * 256 + threadIdx.x;
    if (n >= N_DIM) return;
    float dn = dis[n];
    int p0 = rowp[n], p1 = rowp[n + 1];
    for (int p = p0; p < p1; p++) {
        int e = eid[p];
        int s; float w;
        if (e < E_DIM) { s = ei[e]; w = ew[e]; }
        else           { s = e - E_DIM; w = 1.0f; }
        csrc[p] = s;
        cnrm[p] = dis[s] * w * dn;
    }
}

// ---------------- weight prep: fold W2 into Wih, pack B-fragments ----------------
// fragment idx = ((wv*4+ct)*6+ks)*64 + lane; gate g = 128ct+16wv+r.
// ks 0-1: W'[k][g] = sum_d W2[k][d]*Wih[g][d]   (k = 32ks+8q+j, ah-space)
// ks 2-5: Whh[g][k-64]                          (k-64 = 32(ks-2)+8q+j)
__global__ void k_wprep(const float* __restrict__ W2, const float* __restrict__ Wih,
                        const float* __restrict__ Whh, f16* __restrict__ wfbuf) {
    int idx = blockIdx.x * 256 + threadIdx.x;
    if (idx >= 8 * 4 * 6 * 64) return;
    int lane = idx & 63;
    int ks = (idx >> 6) % 6;
    int ct = ((idx >> 6) / 6) & 3;
    int wv = (idx >> 6) / 24;
    int q = lane >> 4, r = lane & 15;
    int g = 128 * ct + 16 * wv + r;
    f16* dst = wfbuf + (long)idx * 8;
    if (ks < 2) {
        const float* wir = Wih + (long)g * 64;
        #pragma unroll
        for (int j = 0; j < 8; j++) {
            int k = 32 * ks + 8 * q + j;
            const float* w2r = W2 + (long)k * 64;
            float s = 0.f;
            #pragma unroll 16
            for (int d = 0; d < 64; d++) s += w2r[d] * wir[d];
            dst[j] = (f16)s;
        }
    } else {
        const float* src = Whh + (long)g * 128 + 32 * (ks - 2) + 8 * q;
        #pragma unroll
        for (int j = 0; j < 8; j++) dst[j] = (f16)src[j];
    }
}

// gbias[n][g] = bih[g]+bhh[g] + sum_d (b2[d]+county[n][d])*Wih[g][d]
__global__ void k_gbias(const float* __restrict__ county, const float* __restrict__ b2,
                        const float* __restrict__ Wih, const float* __restrict__ bih,
                        const float* __restrict__ bhh, float* __restrict__ gbias) {
    long id = (long)blockIdx.x * 256 + threadIdx.x;
    if (id >= (long)N_DIM * 512) return;
    int n = (int)(id >> 9), g = (int)(id & 511);
    const float* wir = Wih + (long)g * 64;
    const float* cn = county + (long)n * 64;
    float s = bih[g] + bhh[g];
    #pragma unroll 16
    for (int d = 0; d < 64; d++) s += (b2[d] + cn[d]) * wir[d];
    gbias[id] = s;
}

// ---------------- GCN1a: aggX = A.x  (14-dim gather, 4 timesteps/wave) ----------------
__global__ void k_aggx(const float* __restrict__ x, const int* __restrict__ rowp,
                       const int* __restrict__ csrc, const float* __restrict__ cnrm,
                       float* __restrict__ aggX, int tc) {
    int lane = threadIdx.x & 63;
    long wid = ((long)blockIdx.x * 256 + threadIdx.x) >> 6;
    int ntg = (tc + 3) >> 2;
    if (wid >= (long)N_DIM * ntg) return;
    int n = (int)(wid % N_DIM);
    int tg = (int)(wid / N_DIM);
    int j = lane >> 4, d = lane & 15;
    int tj = 4 * tg + j;
    bool live = (d < FEAT) && (tj < tc);
    float acc = 0.f;
    int p0 = rowp[n], p1 = rowp[n + 1];
    for (int p = p0; p < p1; p++) {
        int s = csrc[p];
        float w = cnrm[p];
        if (live) acc += w * x[((long)tj * N_DIM + s) * FEAT + d];
    }
    if (tj < tc) aggX[((long)tj * N_DIM + n) * 16 + d] = acc;
}

// ---------------- GCN1b: h = relu(aggX.W1 + b1) -> f16 ----------------
__global__ void k_tr1(const float* __restrict__ aggX, const float* __restrict__ W1,
                      const float* __restrict__ b1, f16* __restrict__ h, long rows) {
    int lane = threadIdx.x & 63;
    long wid = ((long)blockIdx.x * 256 + threadIdx.x) >> 6;
    float wc[FEAT];
    #pragma unroll
    for (int k = 0; k < FEAT; k++) wc[k] = W1[k * 64 + lane];
    float bb = b1[lane];
    long r0 = wid * 2;
    if (r0 >= rows) return;
    long r1 = r0 + 1;
    bool has1 = (r1 < rows);
    const float* p0 = aggX + r0 * 16;
    const float* p1 = aggX + (has1 ? r1 : r0) * 16;
    float a0 = bb, a1 = bb;
    #pragma unroll
    for (int k = 0; k < FEAT; k++) { a0 += p0[k] * wc[k]; a1 += p1[k] * wc[k]; }
    h[r0 * 64 + lane] = (f16)fmaxf(a0, 0.f);
    if (has1) h[r1 * 64 + lane] = (f16)fmaxf(a1, 0.f);
}

// ---------------- GCN2a: ah = A.h  (f16 gather -> f16 out, 4 timesteps/wave) ----------------
__global__ void k_agg2(const f16* __restrict__ h, const int* __restrict__ rowp,
                       const int* __restrict__ csrc, const float* __restrict__ cnrm,
                       f16* __restrict__ ah, int tc) {
    int lane = threadIdx.x & 63;
    long wid = ((long)blockIdx.x * 256 + threadIdx.x) >> 6;
    int ntg = (tc + 3) >> 2;
    if (wid >= (long)N_DIM * ntg) return;
    int n = (int)(wid % N_DIM);
    int tg = (int)(wid / N_DIM);
    int tbase = 4 * tg;
    float acc0 = 0.f, acc1 = 0.f, acc2 = 0.f, acc3 = 0.f;
    int p0 = rowp[n], p1 = rowp[n + 1];
    for (int p = p0; p < p1; p++) {
        int s = csrc[p];
        float w = cnrm[p];
        const f16* base = h + ((long)tbase * N_DIM + s) * 64 + lane;
        acc0 += w * (float)base[0];
        if (tbase + 1 < tc) acc1 += w * (float)base[(long)N_DIM * 64];
        if (tbase + 2 < tc) acc2 += w * (float)base[(long)N_DIM * 128];
        if (tbase + 3 < tc) acc3 += w * (float)base[(long)N_DIM * 192];
    }
    f16* dst = ah + ((long)tbase * N_DIM + n) * 64 + lane;
    dst[0] = (f16)acc0;
    if (tbase + 1 < tc) dst[(long)N_DIM * 64] = (f16)acc1;
    if (tbase + 2 < tc) dst[(long)N_DIM * 128] = (f16)acc2;
    if (tbase + 3 < tc) dst[(long)N_DIM * 192] = (f16)acc3;
}

// ---------------- LSTM chunk (f16 MFMA, register-pinned weights) + MLP head --------
// Wave wv owns gate-types ct={i,f,g,o} x units [16wv,16wv+16). Thread (wv,q,r):
// nodes 4q+reg, unit u=16wv+r -> all 4 gates of (node,u) live in acc[ct][reg].
__global__ __attribute__((amdgpu_flat_work_group_size(512, 512), amdgpu_waves_per_eu(2, 2)))
void k_lstm(
    const f16* __restrict__ ah, const f16* __restrict__ wfbuf,
    const float* __restrict__ gbias,
    const float* __restrict__ Wm1, const float* __restrict__ bm1,
    const float* __restrict__ Wm2, const float* __restrict__ bm2,
    float* __restrict__ Hst, float* __restrict__ Cst,
    int tc, int do_init, int do_head, float* __restrict__ out) {
    __shared__ __align__(16) f16   xh[2][16][136];   // h (128 units + pad), double-buffered
    __shared__ __align__(16) float hd[16][132];      // head scratch
    __shared__ __align__(16) float zs[16][64];

    int tid = threadIdx.x;
    int wv = tid >> 6, lane = tid & 63, q = lane >> 4, r = lane & 15;
    int nb = blockIdx.x * 16;
    int cnt = min(16, N_DIM - nb);
    int u = 16 * wv + r;

    // prepped weight fragments: 24 coalesced b128 loads, then PIN as asm
    // outputs so the allocator cannot rematerialize them from memory
    // (R5: VGPR_Count=124 proved they were being streamed every step).
    float4_t wfr[4][6];
    #pragma unroll
    for (int ct = 0; ct < 4; ct++)
        #pragma unroll
        for (int ks = 0; ks < 6; ks++)
            wfr[ct][ks] = *(const float4_t*)&wfbuf[(long)((((wv * 4 + ct) * 6 + ks) << 6) + lane) * 8];
    #pragma unroll
    for (int ct = 0; ct < 4; ct++)
        #pragma unroll
        for (int ks = 0; ks < 6; ks++)
            asm volatile("" : "+v"(wfr[ct][ks]));

    // per-node folded bias (b2+county pushed through Wih, plus bih+bhh) -- pinned
    float gb[4][4];
    #pragma unroll
    for (int reg = 0; reg < 4; reg++) {
        int node = 4 * q + reg;
        int gn = nb + node; if (gn >= N_DIM) gn = N_DIM - 1;
        #pragma unroll
        for (int ct = 0; ct < 4; ct++)
            gb[ct][reg] = gbias[(long)gn * 512 + 128 * ct + u];
    }
    #pragma unroll
    for (int ct = 0; ct < 4; ct++)
        #pragma unroll
        for (int reg = 0; reg < 4; reg++)
            asm volatile("" : "+v"(gb[ct][reg]));

    // state in VGPRs
    float cv[4], hvv[4];
    #pragma unroll
    for (int reg = 0; reg < 4; reg++) {
        int node = 4 * q + reg;
        bool live = (!do_init) && (node < cnt);
        hvv[reg] = live ? Hst[(long)(nb + node) * H_DIM + u] : 0.f;
        cv[reg]  = live ? Cst[(long)(nb + node) * H_DIM + u] : 0.f;
        xh[0][node][u] = (f16)hvv[reg];
    }

    int xrow = nb + r; if (xrow >= N_DIM) xrow = N_DIM - 1;
    half8_t xa = *(const half8_t*)(ah + (long)xrow * 64 + 8 * q);
    half8_t xb = *(const half8_t*)(ah + (long)xrow * 64 + 32 + 8 * q);

    int buf = 0;
    __syncthreads();

    for (int t = 0; t < tc; t++) {
        half8_t a2 = *(const half8_t*)&xh[buf][r][8 * q];
        half8_t a3 = *(const half8_t*)&xh[buf][r][32 + 8 * q];
        half8_t a4 = *(const half8_t*)&xh[buf][r][64 + 8 * q];
        half8_t a5 = *(const half8_t*)&xh[buf][r][96 + 8 * q];

        float4_t acc[4];
        #pragma unroll
        for (int ct = 0; ct < 4; ct++) {
            acc[ct][0] = gb[ct][0]; acc[ct][1] = gb[ct][1];
            acc[ct][2] = gb[ct][2]; acc[ct][3] = gb[ct][3];
        }
        #pragma unroll
        for (int ct = 0; ct < 4; ct++)
            acc[ct] = __builtin_amdgcn_mfma_f32_16x16x32_f16(xa, __builtin_bit_cast(half8_t, wfr[ct][0]), acc[ct], 0, 0, 0);
        #pragma unroll
        for (int ct = 0; ct < 4; ct++)
            acc[ct] = __builtin_amdgcn_mfma_f32_16x16x32_f16(xb, __builtin_bit_cast(half8_t, wfr[ct][1]), acc[ct], 0, 0, 0);

        // prefetch next x NOW -- xa/xb just had their last use; the loads get
        // MFMA groups 2-5 + elementwise (~400cy) before the barrier drain.
        int tn = (t + 1 < tc) ? t + 1 : t;
        const f16* xp = ah + ((long)tn * N_DIM + xrow) * 64;
        xa = *(const half8_t*)(xp + 8 * q);
        xb = *(const half8_t*)(xp + 32 + 8 * q);

        #pragma unroll
        for (int ct = 0; ct < 4; ct++)
            acc[ct] = __builtin_amdgcn_mfma_f32_16x16x32_f16(a2, __builtin_bit_cast(half8_t, wfr[ct][2]), acc[ct], 0, 0, 0);
        #pragma unroll
        for (int ct = 0; ct < 4; ct++)
            acc[ct] = __builtin_amdgcn_mfma_f32_16x16x32_f16(a3, __builtin_bit_cast(half8_t, wfr[ct][3]), acc[ct], 0, 0, 0);
        #pragma unroll
        for (int ct = 0; ct < 4; ct++)
            acc[ct] = __builtin_amdgcn_mfma_f32_16x16x32_f16(a4, __builtin_bit_cast(half8_t, wfr[ct][4]), acc[ct], 0, 0, 0);
        #pragma unroll
        for (int ct = 0; ct < 4; ct++)
            acc[ct] = __builtin_amdgcn_mfma_f32_16x16x32_f16(a5, __builtin_bit_cast(half8_t, wfr[ct][5]), acc[ct], 0, 0, 0);

        // elementwise in-register: acc[ct][reg] = gate ct of (node 4q+reg, unit u)
        #pragma unroll
        for (int reg = 0; reg < 4; reg++) {
            float gi = acc[0][reg], gf = acc[1][reg], gg = acc[2][reg], go = acc[3][reg];
            float c = sigf(gf) * cv[reg] + sigf(gi) * tanhfast(gg);
            float hh = sigf(go) * tanhfast(c);
            cv[reg] = c; hvv[reg] = hh;
            xh[buf ^ 1][4 * q + reg][u] = (f16)hh;
        }
        __syncthreads();
        buf ^= 1;
    }

    #pragma unroll
    for (int reg = 0; reg < 4; reg++) {
        int node = 4 * q + reg;
        if (node < cnt) {
            Hst[(long)(nb + node) * H_DIM + u] = hvv[reg];
            Cst[(long)(nb + node) * H_DIM + u] = cv[reg];
        }
    }
    if (!do_head) return;

    #pragma unroll
    for (int reg = 0; reg < 4; reg++) hd[4 * q + reg][u] = hvv[reg];
    __syncthreads();

    for (int i = tid; i < 16 * 64; i += 512) {
        int n = i >> 6, m = i & 63;
        float a = bm1[m];
        #pragma unroll 8
        for (int k = 0; k < H_DIM; k++) a += hd[n][k] * Wm1[k * 64 + m];
        zs[n][m] = fmaxf(a, 0.f);
    }
    __syncthreads();
    if (tid < cnt) {
        float a = bm2[0];
        #pragma unroll 8
        for (int m = 0; m < 64; m++) a += zs[tid][m] * Wm2[m];
        out[nb + tid] = a;
    }
}

// ---------------------------------------------------------------------------

extern "C" void kernel_launch(void* const* d_in, const int* in_sizes, int n_in,
                              void* d_out, int out_size, void* d_ws, size_t ws_size,
                              hipStream_t stream) {
    const float* x   = (const float*)d_in[0];
    const int*   ei  = (const int*)d_in[1];
    const float* ew  = (const float*)d_in[2];
    const float* W1  = (const float*)d_in[3];
    const float* b1  = (const float*)d_in[4];
    const float* W2  = (const float*)d_in[5];
    const float* b2  = (const float*)d_in[6];
    const float* cb  = (const float*)d_in[7];
    const float* Wih = (const float*)d_in[8];
    const float* Whh = (const float*)d_in[9];
    const float* bih = (const float*)d_in[10];
    const float* bhh = (const float*)d_in[11];
    const float* Wm1 = (const float*)d_in[12];
    const float* bm1 = (const float*)d_in[13];
    const float* Wm2 = (const float*)d_in[14];
    const float* bm2 = (const float*)d_in[15];
    float* out = (float*)d_out;
    (void)in_sizes; (void)n_in; (void)out_size;

    char* ws = (char*)d_ws;
    size_t off = 0;
    auto alloc = [&](size_t bytes) -> char* {
        char* p = ws + off;
        off = (off + bytes + 255) & ~(size_t)255;
        return p;
    };
    float* dis   = (float*)alloc(N_DIM * 4);
    int*   cnt   = (int*)alloc(N_DIM * 4);
    int*   fill  = (int*)alloc(N_DIM * 4);
    int*   rowp  = (int*)alloc((N_DIM + 1) * 4);
    int*   eid   = (int*)alloc(ET * 4);
    int*   csrc  = (int*)alloc(ET * 4);
    float* cnrm  = (float*)alloc(ET * 4);
    float* Hst   = (float*)alloc((size_t)N_DIM * H_DIM * 4);
    float* Cst   = (float*)alloc((size_t)N_DIM * H_DIM * 4);
    f16*   wfbuf = (f16*)alloc((size_t)8 * 4 * 6 * 64 * 8 * 2);
    float* gbias = (float*)alloc((size_t)N_DIM * 512 * 4);

    // largest Tc dividing 336 whose chunk buffers (rows*320B) fit
    const int cand[] = {336, 168, 112, 84, 56, 48, 28, 16, 8, 4};
    int Tc = 4;
    for (int i = 0; i < 10; i++) {
        size_t need = off + (size_t)cand[i] * N_DIM * 320 + 4096;
        if (need <= ws_size) { Tc = cand[i]; break; }
    }
    long rows = (long)Tc * N_DIM;
    float* aggX  = (float*)alloc(rows * 64);    // [rows][16] fp32 (14 used)
    f16*   hbuf  = (f16*)alloc(rows * 128);     // h f16
    f16*   ahbuf = (f16*)alloc(rows * 128);     // ah f16

    // --- one-time: CSR build + weight fold/pack + per-node gate bias ---
    k_init<<<(N_DIM + 255) / 256, 256, 0, stream>>>(cnt, fill);
    k_cnt<<<(E_DIM + 255) / 256, 256, 0, stream>>>(ei, cnt);
    k_scan<<<1, 1024, 0, stream>>>(cnt, rowp);
    k_fill<<<(ET + 255) / 256, 256, 0, stream>>>(ei, rowp, fill, eid);
    k_sortdeg<<<(N_DIM + 255) / 256, 256, 0, stream>>>(ew, rowp, eid, dis);
    k_csrmat<<<(N_DIM + 255) / 256, 256, 0, stream>>>(ei, ew, dis, rowp, eid, csrc, cnrm);
    k_wprep<<<48, 256, 0, stream>>>(W2, Wih, Whh, wfbuf);
    k_gbias<<<(int)(((long)N_DIM * 512 + 255) / 256), 256, 0, stream>>>(cb, b2, Wih, bih, bhh, gbias);

    int ntg = (Tc + 3) >> 2;
    long aggWaves = (long)N_DIM * ntg;
    int aggBlocks = (int)((aggWaves + 3) / 4);
    int trBlocks  = (int)(((rows + 1) / 2 + 3) / 4);
    int lblocks   = (N_DIM + 15) / 16;
    int nChunks   = T_DIM / Tc;

    for (int c = 0; c < nChunks; c++) {
        long t0 = (long)c * Tc;
        k_aggx<<<aggBlocks, 256, 0, stream>>>(x + t0 * N_DIM * FEAT, rowp, csrc, cnrm, aggX, Tc);
        k_tr1<<<trBlocks, 256, 0, stream>>>(aggX, W1, b1, hbuf, rows);
        k_agg2<<<aggBlocks, 256, 0, stream>>>(hbuf, rowp, csrc, cnrm, ahbuf, Tc);
        k_lstm<<<lblocks, 512, 0, stream>>>(ahbuf, wfbuf, gbias, Wm1, bm1, Wm2, bm2,
                                            Hst, Cst, Tc, c == 0 ? 1 : 0,
                                            c == nChunks - 1 ? 1 : 0, out);
    }
}